// Round 8
// baseline (2133.039 us; speedup 1.0000x reference)
//
#include <hip/hip_runtime.h>
#include <cstddef>
#include <cstdint>

#define NN 20000
#define NE 640000
#define MP 20096       // padded rows (157*128)
#define KAF 224        // A row length (floats)
#define NC 8
#define CHUNK 80000    // NE / NC
#define NB_SCAN 79     // ceil(NN/256)

__device__ __forceinline__ float h2f(unsigned short u) {
    _Float16 h;
    *reinterpret_cast<unsigned short*>(&h) = u;
    return (float)h;
}
__device__ __forceinline__ unsigned short f2h(float f) {
    _Float16 h = (_Float16)f;
    return *reinterpret_cast<unsigned short*>(&h);
}

// ---------------- setup ----------------
__global__ void zero_kernel(int* __restrict__ p, int n) {
    int i = blockIdx.x * blockDim.x + threadIdx.x;
    if (i < n) p[i] = 0;
}

__global__ void tohf_kernel(const float* __restrict__ in, unsigned short* __restrict__ out, int n) {
    int i = blockIdx.x * blockDim.x + threadIdx.x;
    if (i < n) out[i] = f2h(in[i]);
}

__global__ void hist_kernel(const int* __restrict__ dst, int* __restrict__ cnt) {
    int i = blockIdx.x * blockDim.x + threadIdx.x;
    if (i < NE) atomicAdd(&cnt[(i / CHUNK) * NN + dst[i]], 1);
}

__global__ __launch_bounds__(256) void scan1_kernel(const int* __restrict__ cnt,
                                                    int* __restrict__ lp,
                                                    int* __restrict__ bsum) {
    __shared__ int s[256];
    int t = threadIdx.x;
    int i = blockIdx.x * 256 + t;
    int d = 0;
    if (i < NN)
#pragma unroll
        for (int c = 0; c < NC; ++c) d += cnt[c * NN + i];
    s[t] = d;
    __syncthreads();
    for (int off = 1; off < 256; off <<= 1) {
        int v = (t >= off) ? s[t - off] : 0;
        __syncthreads();
        s[t] += v;
        __syncthreads();
    }
    if (i < NN) lp[i] = s[t] - d;
    if (t == 255) bsum[blockIdx.x] = s[255];
}

__global__ __launch_bounds__(128) void scan2_kernel(const int* __restrict__ bsum,
                                                    int* __restrict__ boff) {
    __shared__ int s[128];
    int t = threadIdx.x;
    int v = (t < NB_SCAN) ? bsum[t] : 0;
    s[t] = v;
    __syncthreads();
    for (int off = 1; off < 128; off <<= 1) {
        int u = (t >= off) ? s[t - off] : 0;
        __syncthreads();
        s[t] += u;
        __syncthreads();
    }
    if (t < NB_SCAN) boff[t] = s[t] - v;
}

__global__ __launch_bounds__(256) void scan3_kernel(const int* __restrict__ cnt,
                                                    const int* __restrict__ lp,
                                                    const int* __restrict__ boff,
                                                    int* __restrict__ row_ptr,
                                                    int* __restrict__ cursor) {
    int i = blockIdx.x * 256 + threadIdx.x;
    if (i < NN) {
        int run = boff[blockIdx.x] + lp[i];
        row_ptr[i] = run;
#pragma unroll
        for (int c = 0; c < NC; ++c) {
            cursor[c * NN + i] = run;
            run += cnt[c * NN + i];
        }
    }
    if (i == 0) row_ptr[NN] = NE;
}

__global__ void place_kernel(const int* __restrict__ src, const int* __restrict__ dst,
                             int* __restrict__ cursor, int2* __restrict__ adj) {
    int i = blockIdx.x * blockDim.x + threadIdx.x;
    if (i < NE) {
        int d = dst[i];
        int pos = atomicAdd(&cursor[(i / CHUNK) * NN + d], 1);
        adj[pos] = make_int2(src[i], i);
    }
}

// esum[v] = sum of incoming-edge features (round-invariant); also degf.
__global__ __launch_bounds__(256) void esum_csr_kernel(
        const float* __restrict__ ef, const int* __restrict__ row_ptr,
        const int2* __restrict__ adj, float* __restrict__ esum,
        float* __restrict__ degf) {
    int wid = threadIdx.x >> 6, lane = threadIdx.x & 63;
    int v = blockIdx.x * 4 + wid;
    if (v >= NN) return;
    int rp0 = row_ptr[v], rp1 = row_ptr[v + 1];
    int q = lane >> 2;
    int fo = (lane & 3) << 2;
    float4 a0 = make_float4(0.f, 0.f, 0.f, 0.f), a1 = a0;
    int i = rp0 + q;
    for (; i + 16 < rp1; i += 32) {
        int e0 = adj[i].y, e1 = adj[i + 16].y;
        float4 x0 = *(const float4*)(ef + (size_t)e0 * 16 + fo);
        float4 x1 = *(const float4*)(ef + (size_t)e1 * 16 + fo);
        a0.x += x0.x; a0.y += x0.y; a0.z += x0.z; a0.w += x0.w;
        a1.x += x1.x; a1.y += x1.y; a1.z += x1.z; a1.w += x1.w;
    }
    for (; i < rp1; i += 16) {
        int e = adj[i].y;
        float4 x = *(const float4*)(ef + (size_t)e * 16 + fo);
        a0.x += x.x; a0.y += x.y; a0.z += x.z; a0.w += x.w;
    }
    a0.x += a1.x; a0.y += a1.y; a0.z += a1.z; a0.w += a1.w;
#pragma unroll
    for (int m = 4; m < 64; m <<= 1) {
        a0.x += __shfl_xor(a0.x, m);
        a0.y += __shfl_xor(a0.y, m);
        a0.z += __shfl_xor(a0.z, m);
        a0.w += __shfl_xor(a0.w, m);
    }
    if (lane < 4) *(float4*)(esum + (size_t)v * 16 + fo) = a0;
    if (lane == 0) degf[v] = (float)(rp1 - rp0);
}

// Fold: WcT[t][j][k] = sum_m W_msg[t][k][m] * W_ih[t][j][m]   (j<192, k<144)
//       bvec[t][j]   = sum_m b_msg[t][m]    * W_ih[t][j][m]
// WcT k layout: [dgh(0:64) | S(64:128) | esum(128:144)]
__global__ __launch_bounds__(192) void fold_kernel(
        const float* __restrict__ W_msg, const float* __restrict__ b_msg,
        const float* __restrict__ W_ih, float* __restrict__ WcT,
        float* __restrict__ bvec) {
    __shared__ float ldsW[64][193];
    int t = blockIdx.x / 9;
    int k0 = (blockIdx.x % 9) * 16;
    int j = threadIdx.x;
    float acc[16];
#pragma unroll
    for (int kk = 0; kk < 16; ++kk) acc[kk] = 0.f;
    float bacc = 0.f;
    for (int mc = 0; mc < 2; ++mc) {
        for (int i = threadIdx.x; i < 192 * 64; i += 192) {
            int jj = i >> 6, mm = i & 63;
            ldsW[mm][jj] = W_ih[((size_t)t * 192 + jj) * 128 + mc * 64 + mm];
        }
        __syncthreads();
        for (int mm = 0; mm < 64; ++mm) {
            float wl = ldsW[mm][j];
            float bm = b_msg[t * 128 + mc * 64 + mm];
            bacc = fmaf(bm, wl, bacc);
#pragma unroll
            for (int kk = 0; kk < 16; ++kk) {
                float wm = W_msg[((size_t)t * 144 + k0 + kk) * 128 + mc * 64 + mm];
                acc[kk] = fmaf(wm, wl, acc[kk]);
            }
        }
        __syncthreads();
    }
#pragma unroll
    for (int kk = 0; kk < 16; ++kk)
        WcT[((size_t)t * 192 + j) * 144 + k0 + kk] = acc[kk];
    if (k0 == 0) bvec[t * 192 + j] = bacc;
}

// BTf[t][n][k] fp32, n<256, k<224, zero-padded; biases folded.
// A layout: [h(0:64) | S(64:128) | dgh(128:192) | esum(192:208) | deg(208) | 1(209) | 0pad]
//  n<192 (r,z cols 0..127 ; i_n cols 128..191):
//    k<64   : n<128 ? W_hh[t][n][k] : 0
//    64..128: WcT[t][n][k]            (S weights, same index)
//    128..192: WcT[t][n][k-128]       (dgh weights)
//    192..208: WcT[t][n][128+k-192]   (esum weights)
//    k==208 : bvec[t][n]
//    k==209 : n<128 ? b_ih+b_hh : b_ih
//  n>=192 (h_n): j=n-64:  k<64 -> W_hh[t][j][k];  k==209 -> b_hh[t][j]; else 0
__global__ void wbig_kernel(const float* __restrict__ WcT, const float* __restrict__ bvec,
                            const float* __restrict__ b_ih, const float* __restrict__ b_hh,
                            const float* __restrict__ W_hh,
                            float* __restrict__ BTf) {
    int idx = blockIdx.x * 256 + threadIdx.x;
    if (idx >= 2 * 256 * KAF) return;
    int t = idx / (256 * KAF);
    int rem = idx % (256 * KAF);
    int n = rem / KAF, k = rem % KAF;
    float v = 0.f;
    if (n < 192) {
        if (k < 64) {
            if (n < 128) v = W_hh[(size_t)t * 192 * 64 + n * 64 + k];
        } else if (k < 128) {
            v = WcT[((size_t)t * 192 + n) * 144 + k];
        } else if (k < 192) {
            v = WcT[((size_t)t * 192 + n) * 144 + (k - 128)];
        } else if (k < 208) {
            v = WcT[((size_t)t * 192 + n) * 144 + 128 + (k - 192)];
        } else if (k == 208) {
            v = bvec[t * 192 + n];
        } else if (k == 209) {
            v = (n < 128) ? (b_ih[t * 192 + n] + b_hh[t * 192 + n]) : b_ih[t * 192 + n];
        }
    } else {
        int j = n - 64;   // 128..191
        if (k < 64) v = W_hh[(size_t)t * 192 * 64 + j * 64 + k];
        else if (k == 209) v = b_hh[t * 192 + j];
    }
    BTf[idx] = v;
}

// round-invariant tail of A: [esum (16) | deg | 1 | zeros]
__global__ void atail_kernel(const float* __restrict__ esum, const float* __restrict__ degf,
                             float* __restrict__ A) {
    int i = blockIdx.x * blockDim.x + threadIdx.x;
    if (i >= NN * 32) return;
    int v = i >> 5, k = 192 + (i & 31);
    float val;
    if (k < 208) val = esum[(size_t)v * 16 + (k - 192)];
    else if (k == 208) val = degf[v];
    else if (k == 209) val = 1.f;
    else val = 0.f;
    A[(size_t)v * KAF + k] = val;
}

// ---------------- per-round ----------------
// A[v][0:192) = [ h (fp32 self) | S = sum_src h_f16 | deg*h ]
__global__ __launch_bounds__(256) void gather_kernel(
        const float* __restrict__ hv, const unsigned short* __restrict__ hf,
        const int* __restrict__ row_ptr, const int2* __restrict__ adj,
        float* __restrict__ A) {
    int wid = threadIdx.x >> 6, lane = threadIdx.x & 63;
    int v = blockIdx.x * 4 + wid;
    if (v >= NN) return;
    int rp0 = row_ptr[v], rp1 = row_ptr[v + 1];
    int q = lane >> 4;
    int fo = (lane & 15) << 2;           // 4 halfs (8B) per lane
    float4 acc[8];
#pragma unroll
    for (int u = 0; u < 8; ++u) acc[u] = make_float4(0.f, 0.f, 0.f, 0.f);
    int i = rp0 + q;
    for (; i + 28 < rp1; i += 32) {
        int s[8];
#pragma unroll
        for (int u = 0; u < 8; ++u) s[u] = adj[i + 4 * u].x;
#pragma unroll
        for (int u = 0; u < 8; ++u) {
            ushort4 x = *(const ushort4*)(hf + (size_t)s[u] * 64 + fo);
            acc[u].x += h2f(x.x); acc[u].y += h2f(x.y);
            acc[u].z += h2f(x.z); acc[u].w += h2f(x.w);
        }
    }
    for (; i + 4 < rp1; i += 8) {
        int s0 = adj[i].x, s1 = adj[i + 4].x;
        ushort4 x0 = *(const ushort4*)(hf + (size_t)s0 * 64 + fo);
        ushort4 x1 = *(const ushort4*)(hf + (size_t)s1 * 64 + fo);
        acc[0].x += h2f(x0.x); acc[0].y += h2f(x0.y);
        acc[0].z += h2f(x0.z); acc[0].w += h2f(x0.w);
        acc[1].x += h2f(x1.x); acc[1].y += h2f(x1.y);
        acc[1].z += h2f(x1.z); acc[1].w += h2f(x1.w);
    }
    for (; i < rp1; i += 4) {
        int s = adj[i].x;
        ushort4 x = *(const ushort4*)(hf + (size_t)s * 64 + fo);
        acc[0].x += h2f(x.x); acc[0].y += h2f(x.y);
        acc[0].z += h2f(x.z); acc[0].w += h2f(x.w);
    }
#pragma unroll
    for (int u = 1; u < 8; ++u) {
        acc[0].x += acc[u].x; acc[0].y += acc[u].y;
        acc[0].z += acc[u].z; acc[0].w += acc[u].w;
    }
#pragma unroll
    for (int m = 16; m < 64; m <<= 1) {
        acc[0].x += __shfl_xor(acc[0].x, m);
        acc[0].y += __shfl_xor(acc[0].y, m);
        acc[0].z += __shfl_xor(acc[0].z, m);
        acc[0].w += __shfl_xor(acc[0].w, m);
    }
    if (lane < 16) {
        float dg = (float)(rp1 - rp0);
        float4 hvv = *(const float4*)(hv + (size_t)v * 64 + fo);
        *(float4*)(A + (size_t)v * KAF + fo) = hvv;
        *(float4*)(A + (size_t)v * KAF + 64 + fo) = acc[0];
        *(float4*)(A + (size_t)v * KAF + 128 + fo) =
            make_float4(dg * hvv.x, dg * hvv.y, dg * hvv.z, dg * hvv.w);
    }
}

// Fused fp32 GEMM (64x256 tile, K=224, per-col-group K-step masks) + GRU gates.
// Col groups: g0=[0,64) r, g1=[64,128) z, g2=[128,192) i_n, g3=[192,256) h_n.
// Active k-steps: g0,g1: all 7; g2: ks>=2; g3: ks<2 || ks==6.
__global__ __launch_bounds__(512) void gemm_gate(
        const float* __restrict__ A, const float* __restrict__ BTf,
        const float* __restrict__ hin,
        float* __restrict__ fout, unsigned short* __restrict__ hfout) {
    __shared__ float As[32][68];     // [k][row], +4 pad
    __shared__ float Bs[32][264];    // [k][n],  +8 pad
    int tid = threadIdx.x;
    int ty = tid >> 5, tx = tid & 31;        // rows ty*4..+4, col pair 2tx within each group
    int row0 = blockIdx.x * 64;
    float acc[4][4][2];
#pragma unroll
    for (int g = 0; g < 4; ++g)
#pragma unroll
        for (int i = 0; i < 4; ++i) { acc[g][i][0] = 0.f; acc[g][i][1] = 0.f; }

    int lr = tid >> 3, lk = (tid & 7) * 4;   // A stage: row lr, k lk..+4
    int ln = tid >> 1, lkb = (tid & 1) * 16; // B stage: n ln, k lkb..+16
    int gB = ln >> 6;

#pragma unroll
    for (int ks = 0; ks < 7; ++ks) {
        int k0 = ks * 32;
        bool a2 = (ks >= 2);
        bool a3 = (ks < 2) || (ks == 6);
        {   // stage A (transposed)
            float4 va = *(const float4*)(A + (size_t)(row0 + lr) * KAF + k0 + lk);
            As[lk + 0][lr] = va.x; As[lk + 1][lr] = va.y;
            As[lk + 2][lr] = va.z; As[lk + 3][lr] = va.w;
        }
        bool actB = (gB < 2) || (gB == 2 ? a2 : a3);
        if (actB) {  // stage B (transposed), skip inactive groups
            const float4* bp = (const float4*)(BTf + (size_t)ln * KAF + k0 + lkb);
            float4 v0 = bp[0], v1 = bp[1], v2 = bp[2], v3 = bp[3];
            Bs[lkb + 0][ln] = v0.x; Bs[lkb + 1][ln] = v0.y;
            Bs[lkb + 2][ln] = v0.z; Bs[lkb + 3][ln] = v0.w;
            Bs[lkb + 4][ln] = v1.x; Bs[lkb + 5][ln] = v1.y;
            Bs[lkb + 6][ln] = v1.z; Bs[lkb + 7][ln] = v1.w;
            Bs[lkb + 8][ln] = v2.x; Bs[lkb + 9][ln] = v2.y;
            Bs[lkb + 10][ln] = v2.z; Bs[lkb + 11][ln] = v2.w;
            Bs[lkb + 12][ln] = v3.x; Bs[lkb + 13][ln] = v3.y;
            Bs[lkb + 14][ln] = v3.z; Bs[lkb + 15][ln] = v3.w;
        }
        __syncthreads();
#pragma unroll
        for (int kk = 0; kk < 32; ++kk) {
            float4 av = *(const float4*)&As[kk][ty * 4];
            float a4[4] = {av.x, av.y, av.z, av.w};
            float2 b0 = *(const float2*)&Bs[kk][2 * tx];
            float2 b1 = *(const float2*)&Bs[kk][64 + 2 * tx];
#pragma unroll
            for (int i = 0; i < 4; ++i) {
                acc[0][i][0] = fmaf(a4[i], b0.x, acc[0][i][0]);
                acc[0][i][1] = fmaf(a4[i], b0.y, acc[0][i][1]);
                acc[1][i][0] = fmaf(a4[i], b1.x, acc[1][i][0]);
                acc[1][i][1] = fmaf(a4[i], b1.y, acc[1][i][1]);
            }
            if (a2) {
                float2 b2 = *(const float2*)&Bs[kk][128 + 2 * tx];
#pragma unroll
                for (int i = 0; i < 4; ++i) {
                    acc[2][i][0] = fmaf(a4[i], b2.x, acc[2][i][0]);
                    acc[2][i][1] = fmaf(a4[i], b2.y, acc[2][i][1]);
                }
            }
            if (a3) {
                float2 b3 = *(const float2*)&Bs[kk][192 + 2 * tx];
#pragma unroll
                for (int i = 0; i < 4; ++i) {
                    acc[3][i][0] = fmaf(a4[i], b3.x, acc[3][i][0]);
                    acc[3][i][1] = fmaf(a4[i], b3.y, acc[3][i][1]);
                }
            }
        }
        __syncthreads();
    }

    // epilogue: GRU gates
#pragma unroll
    for (int i = 0; i < 4; ++i) {
        int row = row0 + ty * 4 + i;
        if (row >= NN) continue;
#pragma unroll
        for (int c = 0; c < 2; ++c) {
            int j = 2 * tx + c;
            float rr = acc[0][i][c];
            float zz = acc[1][i][c];
            float in_ = acc[2][i][c];
            float hn = acc[3][i][c];
            float r = 1.f / (1.f + __expf(-rr));
            float z = 1.f / (1.f + __expf(-zz));
            float n = tanhf(in_ + r * hn);
            float h = hin[(size_t)row * 64 + j];
            float val = (1.f - z) * n + z * h;
            fout[(size_t)row * 64 + j] = val;
            hfout[(size_t)row * 64 + j] = f2h(val);
        }
    }
}

extern "C" void kernel_launch(void* const* d_in, const int* in_sizes, int n_in,
                              void* d_out, int out_size, void* d_ws, size_t ws_size,
                              hipStream_t stream) {
    const float* hv0   = (const float*)d_in[0];
    const float* ef    = (const float*)d_in[1];
    const int*   src   = (const int*)d_in[2];
    const int*   dst   = (const int*)d_in[3];
    const float* W_msg = (const float*)d_in[4];
    const float* b_msg = (const float*)d_in[5];
    const float* W_ih  = (const float*)d_in[6];
    const float* W_hh  = (const float*)d_in[7];
    const float* b_ih  = (const float*)d_in[8];
    const float* b_hh  = (const float*)d_in[9];
    float* out = (float*)d_out;

    char* ws = (char*)d_ws;
    size_t off = 0;
    auto alloc = [&](size_t bytes) -> char* {
        char* p = ws + off;
        off = (off + bytes + 255) & ~(size_t)255;
        return p;
    };
    int*   cnt      = (int*)alloc((size_t)NC * NN * 4);
    int*   row_ptr  = (int*)alloc((NN + 1) * 4);
    int*   cursor   = (int*)alloc((size_t)NC * NN * 4);
    int2*  adj      = (int2*)alloc((size_t)NE * 8);
    float* esum     = (float*)alloc((size_t)NN * 16 * 4);
    float* degf     = (float*)alloc(NN * 4);
    float* WcT      = (float*)alloc((size_t)2 * 192 * 144 * 4);
    float* bvec     = (float*)alloc(2 * 192 * 4);
    int*   lp       = (int*)alloc(NN * 4);
    int*   bsum     = (int*)alloc(NB_SCAN * 4);
    int*   boff     = (int*)alloc(NB_SCAN * 4);
    float* A        = (float*)alloc((size_t)MP * KAF * 4);
    float* BTf      = (float*)alloc((size_t)2 * 256 * KAF * 4);
    float* hv1      = (float*)alloc((size_t)NN * 64 * 4);
    unsigned short* hf0 = (unsigned short*)alloc((size_t)NN * 64 * 2);
    unsigned short* hf1 = (unsigned short*)alloc((size_t)NN * 64 * 2);

    zero_kernel<<<(NC * NN + 1023) / 1024, 1024, 0, stream>>>(cnt, NC * NN);
    tohf_kernel<<<(NN * 64 + 255) / 256, 256, 0, stream>>>(hv0, hf0, NN * 64);
    hist_kernel<<<(NE + 255) / 256, 256, 0, stream>>>(dst, cnt);
    scan1_kernel<<<NB_SCAN, 256, 0, stream>>>(cnt, lp, bsum);
    scan2_kernel<<<1, 128, 0, stream>>>(bsum, boff);
    scan3_kernel<<<NB_SCAN, 256, 0, stream>>>(cnt, lp, boff, row_ptr, cursor);
    place_kernel<<<(NE + 255) / 256, 256, 0, stream>>>(src, dst, cursor, adj);
    esum_csr_kernel<<<(NN + 3) / 4, 256, 0, stream>>>(ef, row_ptr, adj, esum, degf);
    fold_kernel<<<18, 192, 0, stream>>>(W_msg, b_msg, W_ih, WcT, bvec);
    wbig_kernel<<<(2 * 256 * KAF + 255) / 256, 256, 0, stream>>>(WcT, bvec, b_ih, b_hh, W_hh, BTf);
    atail_kernel<<<(NN * 32 + 255) / 256, 256, 0, stream>>>(esum, degf, A);

    for (int t = 0; t < 2; ++t) {
        const float* hin = (t == 0) ? hv0 : hv1;
        const unsigned short* hfin = (t == 0) ? hf0 : hf1;
        float* hout = (t == 1) ? out : hv1;
        gather_kernel<<<(NN + 3) / 4, 256, 0, stream>>>(hin, hfin, row_ptr, adj, A);
        gemm_gate<<<MP / 64, 512, 0, stream>>>(A, BTf + (size_t)t * 256 * KAF,
                                               hin, hout, hf1);
    }
}

// Round 9
// 580.554 us; speedup vs baseline: 3.6741x; 3.6741x over previous
//
#include <hip/hip_runtime.h>
#include <cstddef>
#include <cstdint>

#define NN 20000
#define NE 640000
#define MP 20096       // padded rows (157*128)
#define KAF 224        // A row length (floats)
#define NC 8
#define CHUNK 80000    // NE / NC
#define NB_SCAN 79     // ceil(NN/256)

__device__ __forceinline__ float h2f(unsigned short u) {
    _Float16 h;
    *reinterpret_cast<unsigned short*>(&h) = u;
    return (float)h;
}
__device__ __forceinline__ unsigned short f2h(float f) {
    _Float16 h = (_Float16)f;
    return *reinterpret_cast<unsigned short*>(&h);
}

// ---------------- setup ----------------
__global__ void zero_kernel(int* __restrict__ p, int n) {
    int i = blockIdx.x * blockDim.x + threadIdx.x;
    if (i < n) p[i] = 0;
}

__global__ void tohf_kernel(const float* __restrict__ in, unsigned short* __restrict__ out, int n) {
    int i = blockIdx.x * blockDim.x + threadIdx.x;
    if (i < n) out[i] = f2h(in[i]);
}

__global__ void hist_kernel(const int* __restrict__ dst, int* __restrict__ cnt) {
    int i = blockIdx.x * blockDim.x + threadIdx.x;
    if (i < NE) atomicAdd(&cnt[(i / CHUNK) * NN + dst[i]], 1);
}

__global__ __launch_bounds__(256) void scan1_kernel(const int* __restrict__ cnt,
                                                    int* __restrict__ lp,
                                                    int* __restrict__ bsum) {
    __shared__ int s[256];
    int t = threadIdx.x;
    int i = blockIdx.x * 256 + t;
    int d = 0;
    if (i < NN)
#pragma unroll
        for (int c = 0; c < NC; ++c) d += cnt[c * NN + i];
    s[t] = d;
    __syncthreads();
    for (int off = 1; off < 256; off <<= 1) {
        int v = (t >= off) ? s[t - off] : 0;
        __syncthreads();
        s[t] += v;
        __syncthreads();
    }
    if (i < NN) lp[i] = s[t] - d;
    if (t == 255) bsum[blockIdx.x] = s[255];
}

__global__ __launch_bounds__(128) void scan2_kernel(const int* __restrict__ bsum,
                                                    int* __restrict__ boff) {
    __shared__ int s[128];
    int t = threadIdx.x;
    int v = (t < NB_SCAN) ? bsum[t] : 0;
    s[t] = v;
    __syncthreads();
    for (int off = 1; off < 128; off <<= 1) {
        int u = (t >= off) ? s[t - off] : 0;
        __syncthreads();
        s[t] += u;
        __syncthreads();
    }
    if (t < NB_SCAN) boff[t] = s[t] - v;
}

__global__ __launch_bounds__(256) void scan3_kernel(const int* __restrict__ cnt,
                                                    const int* __restrict__ lp,
                                                    const int* __restrict__ boff,
                                                    int* __restrict__ row_ptr,
                                                    int* __restrict__ cursor) {
    int i = blockIdx.x * 256 + threadIdx.x;
    if (i < NN) {
        int run = boff[blockIdx.x] + lp[i];
        row_ptr[i] = run;
#pragma unroll
        for (int c = 0; c < NC; ++c) {
            cursor[c * NN + i] = run;
            run += cnt[c * NN + i];
        }
    }
    if (i == 0) row_ptr[NN] = NE;
}

__global__ void place_kernel(const int* __restrict__ src, const int* __restrict__ dst,
                             int* __restrict__ cursor, int2* __restrict__ adj) {
    int i = blockIdx.x * blockDim.x + threadIdx.x;
    if (i < NE) {
        int d = dst[i];
        int pos = atomicAdd(&cursor[(i / CHUNK) * NN + d], 1);
        adj[pos] = make_int2(src[i], i);
    }
}

// esum[v] = sum of incoming-edge features (round-invariant); also degf.
__global__ __launch_bounds__(256) void esum_csr_kernel(
        const float* __restrict__ ef, const int* __restrict__ row_ptr,
        const int2* __restrict__ adj, float* __restrict__ esum,
        float* __restrict__ degf) {
    int wid = threadIdx.x >> 6, lane = threadIdx.x & 63;
    int v = blockIdx.x * 4 + wid;
    if (v >= NN) return;
    int rp0 = row_ptr[v], rp1 = row_ptr[v + 1];
    int q = lane >> 2;
    int fo = (lane & 3) << 2;
    float4 a0 = make_float4(0.f, 0.f, 0.f, 0.f), a1 = a0;
    int i = rp0 + q;
    for (; i + 16 < rp1; i += 32) {
        int e0 = adj[i].y, e1 = adj[i + 16].y;
        float4 x0 = *(const float4*)(ef + (size_t)e0 * 16 + fo);
        float4 x1 = *(const float4*)(ef + (size_t)e1 * 16 + fo);
        a0.x += x0.x; a0.y += x0.y; a0.z += x0.z; a0.w += x0.w;
        a1.x += x1.x; a1.y += x1.y; a1.z += x1.z; a1.w += x1.w;
    }
    for (; i < rp1; i += 16) {
        int e = adj[i].y;
        float4 x = *(const float4*)(ef + (size_t)e * 16 + fo);
        a0.x += x.x; a0.y += x.y; a0.z += x.z; a0.w += x.w;
    }
    a0.x += a1.x; a0.y += a1.y; a0.z += a1.z; a0.w += a1.w;
#pragma unroll
    for (int m = 4; m < 64; m <<= 1) {
        a0.x += __shfl_xor(a0.x, m);
        a0.y += __shfl_xor(a0.y, m);
        a0.z += __shfl_xor(a0.z, m);
        a0.w += __shfl_xor(a0.w, m);
    }
    if (lane < 4) *(float4*)(esum + (size_t)v * 16 + fo) = a0;
    if (lane == 0) degf[v] = (float)(rp1 - rp0);
}

// Fold: WcT[t][j][k] = sum_m W_msg[t][k][m] * W_ih[t][j][m]   (j<192, k<144)
//       bvec[t][j]   = sum_m b_msg[t][m]    * W_ih[t][j][m]
__global__ __launch_bounds__(192) void fold_kernel(
        const float* __restrict__ W_msg, const float* __restrict__ b_msg,
        const float* __restrict__ W_ih, float* __restrict__ WcT,
        float* __restrict__ bvec) {
    __shared__ float ldsW[64][193];
    int t = blockIdx.x / 9;
    int k0 = (blockIdx.x % 9) * 16;
    int j = threadIdx.x;
    float acc[16];
#pragma unroll
    for (int kk = 0; kk < 16; ++kk) acc[kk] = 0.f;
    float bacc = 0.f;
    for (int mc = 0; mc < 2; ++mc) {
        for (int i = threadIdx.x; i < 192 * 64; i += 192) {
            int jj = i >> 6, mm = i & 63;
            ldsW[mm][jj] = W_ih[((size_t)t * 192 + jj) * 128 + mc * 64 + mm];
        }
        __syncthreads();
        for (int mm = 0; mm < 64; ++mm) {
            float wl = ldsW[mm][j];
            float bm = b_msg[t * 128 + mc * 64 + mm];
            bacc = fmaf(bm, wl, bacc);
#pragma unroll
            for (int kk = 0; kk < 16; ++kk) {
                float wm = W_msg[((size_t)t * 144 + k0 + kk) * 128 + mc * 64 + mm];
                acc[kk] = fmaf(wm, wl, acc[kk]);
            }
        }
        __syncthreads();
    }
#pragma unroll
    for (int kk = 0; kk < 16; ++kk)
        WcT[((size_t)t * 192 + j) * 144 + k0 + kk] = acc[kk];
    if (k0 == 0) bvec[t * 192 + j] = bacc;
}

// BTf[t][n][k] fp32, n<256, k<224, zero-padded; biases folded.
// A layout: [h(0:64) | S(64:128) | dgh(128:192) | esum(192:208) | deg(208) | 1(209) | 0pad]
__global__ void wbig_kernel(const float* __restrict__ WcT, const float* __restrict__ bvec,
                            const float* __restrict__ b_ih, const float* __restrict__ b_hh,
                            const float* __restrict__ W_hh,
                            float* __restrict__ BTf) {
    int idx = blockIdx.x * 256 + threadIdx.x;
    if (idx >= 2 * 256 * KAF) return;
    int t = idx / (256 * KAF);
    int rem = idx % (256 * KAF);
    int n = rem / KAF, k = rem % KAF;
    float v = 0.f;
    if (n < 192) {
        if (k < 64) {
            if (n < 128) v = W_hh[(size_t)t * 192 * 64 + n * 64 + k];
        } else if (k < 128) {
            v = WcT[((size_t)t * 192 + n) * 144 + k];
        } else if (k < 192) {
            v = WcT[((size_t)t * 192 + n) * 144 + (k - 128)];
        } else if (k < 208) {
            v = WcT[((size_t)t * 192 + n) * 144 + 128 + (k - 192)];
        } else if (k == 208) {
            v = bvec[t * 192 + n];
        } else if (k == 209) {
            v = (n < 128) ? (b_ih[t * 192 + n] + b_hh[t * 192 + n]) : b_ih[t * 192 + n];
        }
    } else {
        int j = n - 64;   // 128..191
        if (k < 64) v = W_hh[(size_t)t * 192 * 64 + j * 64 + k];
        else if (k == 209) v = b_hh[t * 192 + j];
    }
    BTf[idx] = v;
}

// round-invariant tail of A: [esum (16) | deg | 1 | zeros]
__global__ void atail_kernel(const float* __restrict__ esum, const float* __restrict__ degf,
                             float* __restrict__ A) {
    int i = blockIdx.x * blockDim.x + threadIdx.x;
    if (i >= NN * 32) return;
    int v = i >> 5, k = 192 + (i & 31);
    float val;
    if (k < 208) val = esum[(size_t)v * 16 + (k - 192)];
    else if (k == 208) val = degf[v];
    else if (k == 209) val = 1.f;
    else val = 0.f;
    A[(size_t)v * KAF + k] = val;
}

// ---------------- per-round ----------------
// A[v][0:192) = [ h (fp32 self) | S = sum_src h_f16 | deg*h ]
__global__ __launch_bounds__(256) void gather_kernel(
        const float* __restrict__ hv, const unsigned short* __restrict__ hf,
        const int* __restrict__ row_ptr, const int2* __restrict__ adj,
        float* __restrict__ A) {
    int wid = threadIdx.x >> 6, lane = threadIdx.x & 63;
    int v = blockIdx.x * 4 + wid;
    if (v >= NN) return;
    int rp0 = row_ptr[v], rp1 = row_ptr[v + 1];
    int q = lane >> 4;
    int fo = (lane & 15) << 2;           // 4 halfs (8B) per lane
    float4 acc[8];
#pragma unroll
    for (int u = 0; u < 8; ++u) acc[u] = make_float4(0.f, 0.f, 0.f, 0.f);
    int i = rp0 + q;
    for (; i + 28 < rp1; i += 32) {
        int s[8];
#pragma unroll
        for (int u = 0; u < 8; ++u) s[u] = adj[i + 4 * u].x;
#pragma unroll
        for (int u = 0; u < 8; ++u) {
            ushort4 x = *(const ushort4*)(hf + (size_t)s[u] * 64 + fo);
            acc[u].x += h2f(x.x); acc[u].y += h2f(x.y);
            acc[u].z += h2f(x.z); acc[u].w += h2f(x.w);
        }
    }
    for (; i + 4 < rp1; i += 8) {
        int s0 = adj[i].x, s1 = adj[i + 4].x;
        ushort4 x0 = *(const ushort4*)(hf + (size_t)s0 * 64 + fo);
        ushort4 x1 = *(const ushort4*)(hf + (size_t)s1 * 64 + fo);
        acc[0].x += h2f(x0.x); acc[0].y += h2f(x0.y);
        acc[0].z += h2f(x0.z); acc[0].w += h2f(x0.w);
        acc[1].x += h2f(x1.x); acc[1].y += h2f(x1.y);
        acc[1].z += h2f(x1.z); acc[1].w += h2f(x1.w);
    }
    for (; i < rp1; i += 4) {
        int s = adj[i].x;
        ushort4 x = *(const ushort4*)(hf + (size_t)s * 64 + fo);
        acc[0].x += h2f(x.x); acc[0].y += h2f(x.y);
        acc[0].z += h2f(x.z); acc[0].w += h2f(x.w);
    }
#pragma unroll
    for (int u = 1; u < 8; ++u) {
        acc[0].x += acc[u].x; acc[0].y += acc[u].y;
        acc[0].z += acc[u].z; acc[0].w += acc[u].w;
    }
#pragma unroll
    for (int m = 16; m < 64; m <<= 1) {
        acc[0].x += __shfl_xor(acc[0].x, m);
        acc[0].y += __shfl_xor(acc[0].y, m);
        acc[0].z += __shfl_xor(acc[0].z, m);
        acc[0].w += __shfl_xor(acc[0].w, m);
    }
    if (lane < 16) {
        float dg = (float)(rp1 - rp0);
        float4 hvv = *(const float4*)(hv + (size_t)v * 64 + fo);
        *(float4*)(A + (size_t)v * KAF + fo) = hvv;
        *(float4*)(A + (size_t)v * KAF + 64 + fo) = acc[0];
        *(float4*)(A + (size_t)v * KAF + 128 + fo) =
            make_float4(dg * hvv.x, dg * hvv.y, dg * hvv.z, dg * hvv.w);
    }
}

// Fused fp32 GEMM (64x256 tile, K=224, per-col-group K-step masks) + GRU gates.
// Col groups: g0=[0,64) r, g1=[64,128) z, g2=[128,192) i_n, g3=[192,256) h_n.
// Active k-steps: g0,g1: all 7; g2: ks>=2; g3: ks<2 || ks==6.
// NOTE: ks loop must NOT be unrolled — R8 post-mortem: full unroll hoisted all
// staging loads, blew registers, spilled acc -> 2.4 GB scratch traffic.
__global__ __launch_bounds__(512) void gemm_gate(
        const float* __restrict__ A, const float* __restrict__ BTf,
        const float* __restrict__ hin,
        float* __restrict__ fout, unsigned short* __restrict__ hfout) {
    __shared__ float As[32][68];     // [k][row], +4 pad
    __shared__ float Bs[32][264];    // [k][n],  +8 pad
    int tid = threadIdx.x;
    int ty = tid >> 5, tx = tid & 31;        // rows ty*4..+4, col pair 2tx per group
    int row0 = blockIdx.x * 64;
    float acc[4][4][2];
#pragma unroll
    for (int g = 0; g < 4; ++g)
#pragma unroll
        for (int i = 0; i < 4; ++i) { acc[g][i][0] = 0.f; acc[g][i][1] = 0.f; }

    int lr = tid >> 3, lk = (tid & 7) * 4;   // A stage: row lr, k lk..+4
    int ln = tid >> 1, lkb = (tid & 1) * 16; // B stage: n ln, k lkb..+16
    int gB = ln >> 6;

#pragma unroll 1
    for (int ks = 0; ks < 7; ++ks) {
        int k0 = ks * 32;
        bool a2 = (ks >= 2);
        bool a3 = (ks < 2) || (ks == 6);
        {   // stage A (transposed)
            float4 va = *(const float4*)(A + (size_t)(row0 + lr) * KAF + k0 + lk);
            As[lk + 0][lr] = va.x; As[lk + 1][lr] = va.y;
            As[lk + 2][lr] = va.z; As[lk + 3][lr] = va.w;
        }
        bool actB = (gB < 2) || (gB == 2 ? a2 : a3);
        if (actB) {  // stage B (transposed), skip inactive groups
            const float4* bp = (const float4*)(BTf + (size_t)ln * KAF + k0 + lkb);
            float4 v0 = bp[0], v1 = bp[1], v2 = bp[2], v3 = bp[3];
            Bs[lkb + 0][ln] = v0.x; Bs[lkb + 1][ln] = v0.y;
            Bs[lkb + 2][ln] = v0.z; Bs[lkb + 3][ln] = v0.w;
            Bs[lkb + 4][ln] = v1.x; Bs[lkb + 5][ln] = v1.y;
            Bs[lkb + 6][ln] = v1.z; Bs[lkb + 7][ln] = v1.w;
            Bs[lkb + 8][ln] = v2.x; Bs[lkb + 9][ln] = v2.y;
            Bs[lkb + 10][ln] = v2.z; Bs[lkb + 11][ln] = v2.w;
            Bs[lkb + 12][ln] = v3.x; Bs[lkb + 13][ln] = v3.y;
            Bs[lkb + 14][ln] = v3.z; Bs[lkb + 15][ln] = v3.w;
        }
        __syncthreads();
#pragma unroll
        for (int kk = 0; kk < 32; ++kk) {
            float4 av = *(const float4*)&As[kk][ty * 4];
            float a4[4] = {av.x, av.y, av.z, av.w};
            float2 b0 = *(const float2*)&Bs[kk][2 * tx];
            float2 b1 = *(const float2*)&Bs[kk][64 + 2 * tx];
#pragma unroll
            for (int i = 0; i < 4; ++i) {
                acc[0][i][0] = fmaf(a4[i], b0.x, acc[0][i][0]);
                acc[0][i][1] = fmaf(a4[i], b0.y, acc[0][i][1]);
                acc[1][i][0] = fmaf(a4[i], b1.x, acc[1][i][0]);
                acc[1][i][1] = fmaf(a4[i], b1.y, acc[1][i][1]);
            }
            if (a2) {
                float2 b2 = *(const float2*)&Bs[kk][128 + 2 * tx];
#pragma unroll
                for (int i = 0; i < 4; ++i) {
                    acc[2][i][0] = fmaf(a4[i], b2.x, acc[2][i][0]);
                    acc[2][i][1] = fmaf(a4[i], b2.y, acc[2][i][1]);
                }
            }
            if (a3) {
                float2 b3 = *(const float2*)&Bs[kk][192 + 2 * tx];
#pragma unroll
                for (int i = 0; i < 4; ++i) {
                    acc[3][i][0] = fmaf(a4[i], b3.x, acc[3][i][0]);
                    acc[3][i][1] = fmaf(a4[i], b3.y, acc[3][i][1]);
                }
            }
        }
        __syncthreads();
    }

    // epilogue: GRU gates
#pragma unroll
    for (int i = 0; i < 4; ++i) {
        int row = row0 + ty * 4 + i;
        if (row >= NN) continue;
#pragma unroll
        for (int c = 0; c < 2; ++c) {
            int j = 2 * tx + c;
            float rr = acc[0][i][c];
            float zz = acc[1][i][c];
            float in_ = acc[2][i][c];
            float hn = acc[3][i][c];
            float r = 1.f / (1.f + __expf(-rr));
            float z = 1.f / (1.f + __expf(-zz));
            float n = tanhf(in_ + r * hn);
            float h = hin[(size_t)row * 64 + j];
            float val = (1.f - z) * n + z * h;
            fout[(size_t)row * 64 + j] = val;
            hfout[(size_t)row * 64 + j] = f2h(val);
        }
    }
}

extern "C" void kernel_launch(void* const* d_in, const int* in_sizes, int n_in,
                              void* d_out, int out_size, void* d_ws, size_t ws_size,
                              hipStream_t stream) {
    const float* hv0   = (const float*)d_in[0];
    const float* ef    = (const float*)d_in[1];
    const int*   src   = (const int*)d_in[2];
    const int*   dst   = (const int*)d_in[3];
    const float* W_msg = (const float*)d_in[4];
    const float* b_msg = (const float*)d_in[5];
    const float* W_ih  = (const float*)d_in[6];
    const float* W_hh  = (const float*)d_in[7];
    const float* b_ih  = (const float*)d_in[8];
    const float* b_hh  = (const float*)d_in[9];
    float* out = (float*)d_out;

    char* ws = (char*)d_ws;
    size_t off = 0;
    auto alloc = [&](size_t bytes) -> char* {
        char* p = ws + off;
        off = (off + bytes + 255) & ~(size_t)255;
        return p;
    };
    int*   cnt      = (int*)alloc((size_t)NC * NN * 4);
    int*   row_ptr  = (int*)alloc((NN + 1) * 4);
    int*   cursor   = (int*)alloc((size_t)NC * NN * 4);
    int2*  adj      = (int2*)alloc((size_t)NE * 8);
    float* esum     = (float*)alloc((size_t)NN * 16 * 4);
    float* degf     = (float*)alloc(NN * 4);
    float* WcT      = (float*)alloc((size_t)2 * 192 * 144 * 4);
    float* bvec     = (float*)alloc(2 * 192 * 4);
    int*   lp       = (int*)alloc(NN * 4);
    int*   bsum     = (int*)alloc(NB_SCAN * 4);
    int*   boff     = (int*)alloc(NB_SCAN * 4);
    float* A        = (float*)alloc((size_t)MP * KAF * 4);
    float* BTf      = (float*)alloc((size_t)2 * 256 * KAF * 4);
    float* hv1      = (float*)alloc((size_t)NN * 64 * 4);
    unsigned short* hf0 = (unsigned short*)alloc((size_t)NN * 64 * 2);
    unsigned short* hf1 = (unsigned short*)alloc((size_t)NN * 64 * 2);

    zero_kernel<<<(NC * NN + 1023) / 1024, 1024, 0, stream>>>(cnt, NC * NN);
    tohf_kernel<<<(NN * 64 + 255) / 256, 256, 0, stream>>>(hv0, hf0, NN * 64);
    hist_kernel<<<(NE + 255) / 256, 256, 0, stream>>>(dst, cnt);
    scan1_kernel<<<NB_SCAN, 256, 0, stream>>>(cnt, lp, bsum);
    scan2_kernel<<<1, 128, 0, stream>>>(bsum, boff);
    scan3_kernel<<<NB_SCAN, 256, 0, stream>>>(cnt, lp, boff, row_ptr, cursor);
    place_kernel<<<(NE + 255) / 256, 256, 0, stream>>>(src, dst, cursor, adj);
    esum_csr_kernel<<<(NN + 3) / 4, 256, 0, stream>>>(ef, row_ptr, adj, esum, degf);
    fold_kernel<<<18, 192, 0, stream>>>(W_msg, b_msg, W_ih, WcT, bvec);
    wbig_kernel<<<(2 * 256 * KAF + 255) / 256, 256, 0, stream>>>(WcT, bvec, b_ih, b_hh, W_hh, BTf);
    atail_kernel<<<(NN * 32 + 255) / 256, 256, 0, stream>>>(esum, degf, A);

    for (int t = 0; t < 2; ++t) {
        const float* hin = (t == 0) ? hv0 : hv1;
        const unsigned short* hfin = (t == 0) ? hf0 : hf1;
        float* hout = (t == 1) ? out : hv1;
        gather_kernel<<<(NN + 3) / 4, 256, 0, stream>>>(hin, hfin, row_ptr, adj, A);
        gemm_gate<<<MP / 64, 512, 0, stream>>>(A, BTf + (size_t)t * 256 * KAF,
                                               hin, hout, hf1);
    }
}

// Round 10
// 343.136 us; speedup vs baseline: 6.2163x; 1.6919x over previous
//
#include <hip/hip_runtime.h>
#include <cstddef>
#include <cstdint>

#define NN 20000
#define NE 640000
#define MP 20096       // padded rows (157*128)
#define KAF 224        // A row length (floats)
#define NC 8
#define CHUNK 80000    // NE / NC
#define NB_SCAN 79     // ceil(NN/256)

__device__ __forceinline__ float h2f(unsigned short u) {
    _Float16 h;
    *reinterpret_cast<unsigned short*>(&h) = u;
    return (float)h;
}
__device__ __forceinline__ unsigned short f2h(float f) {
    _Float16 h = (_Float16)f;
    return *reinterpret_cast<unsigned short*>(&h);
}

// ---------------- setup ----------------
__global__ void zero_kernel(int* __restrict__ p, int n) {
    int i = blockIdx.x * blockDim.x + threadIdx.x;
    if (i < n) p[i] = 0;
}

__global__ void tohf_kernel(const float* __restrict__ in, unsigned short* __restrict__ out, int n) {
    int i = blockIdx.x * blockDim.x + threadIdx.x;
    if (i < n) out[i] = f2h(in[i]);
}

__global__ void hist_kernel(const int* __restrict__ dst, int* __restrict__ cnt) {
    int i = blockIdx.x * blockDim.x + threadIdx.x;
    if (i < NE) atomicAdd(&cnt[(i / CHUNK) * NN + dst[i]], 1);
}

__global__ __launch_bounds__(256) void scan1_kernel(const int* __restrict__ cnt,
                                                    int* __restrict__ lp,
                                                    int* __restrict__ bsum) {
    __shared__ int s[256];
    int t = threadIdx.x;
    int i = blockIdx.x * 256 + t;
    int d = 0;
    if (i < NN)
#pragma unroll
        for (int c = 0; c < NC; ++c) d += cnt[c * NN + i];
    s[t] = d;
    __syncthreads();
    for (int off = 1; off < 256; off <<= 1) {
        int v = (t >= off) ? s[t - off] : 0;
        __syncthreads();
        s[t] += v;
        __syncthreads();
    }
    if (i < NN) lp[i] = s[t] - d;
    if (t == 255) bsum[blockIdx.x] = s[255];
}

__global__ __launch_bounds__(128) void scan2_kernel(const int* __restrict__ bsum,
                                                    int* __restrict__ boff) {
    __shared__ int s[128];
    int t = threadIdx.x;
    int v = (t < NB_SCAN) ? bsum[t] : 0;
    s[t] = v;
    __syncthreads();
    for (int off = 1; off < 128; off <<= 1) {
        int u = (t >= off) ? s[t - off] : 0;
        __syncthreads();
        s[t] += u;
        __syncthreads();
    }
    if (t < NB_SCAN) boff[t] = s[t] - v;
}

__global__ __launch_bounds__(256) void scan3_kernel(const int* __restrict__ cnt,
                                                    const int* __restrict__ lp,
                                                    const int* __restrict__ boff,
                                                    int* __restrict__ row_ptr,
                                                    int* __restrict__ cursor) {
    int i = blockIdx.x * 256 + threadIdx.x;
    if (i < NN) {
        int run = boff[blockIdx.x] + lp[i];
        row_ptr[i] = run;
#pragma unroll
        for (int c = 0; c < NC; ++c) {
            cursor[c * NN + i] = run;
            run += cnt[c * NN + i];
        }
    }
    if (i == 0) row_ptr[NN] = NE;
}

__global__ void place_kernel(const int* __restrict__ src, const int* __restrict__ dst,
                             int* __restrict__ cursor, int2* __restrict__ adj) {
    int i = blockIdx.x * blockDim.x + threadIdx.x;
    if (i < NE) {
        int d = dst[i];
        int pos = atomicAdd(&cursor[(i / CHUNK) * NN + d], 1);
        adj[pos] = make_int2(src[i], i);
    }
}

// esum[v] = sum of incoming-edge features (round-invariant); also degf.
__global__ __launch_bounds__(256) void esum_csr_kernel(
        const float* __restrict__ ef, const int* __restrict__ row_ptr,
        const int2* __restrict__ adj, float* __restrict__ esum,
        float* __restrict__ degf) {
    int wid = threadIdx.x >> 6, lane = threadIdx.x & 63;
    int v = blockIdx.x * 4 + wid;
    if (v >= NN) return;
    int rp0 = row_ptr[v], rp1 = row_ptr[v + 1];
    int q = lane >> 2;
    int fo = (lane & 3) << 2;
    float4 a0 = make_float4(0.f, 0.f, 0.f, 0.f), a1 = a0;
    int i = rp0 + q;
    for (; i + 16 < rp1; i += 32) {
        int e0 = adj[i].y, e1 = adj[i + 16].y;
        float4 x0 = *(const float4*)(ef + (size_t)e0 * 16 + fo);
        float4 x1 = *(const float4*)(ef + (size_t)e1 * 16 + fo);
        a0.x += x0.x; a0.y += x0.y; a0.z += x0.z; a0.w += x0.w;
        a1.x += x1.x; a1.y += x1.y; a1.z += x1.z; a1.w += x1.w;
    }
    for (; i < rp1; i += 16) {
        int e = adj[i].y;
        float4 x = *(const float4*)(ef + (size_t)e * 16 + fo);
        a0.x += x.x; a0.y += x.y; a0.z += x.z; a0.w += x.w;
    }
    a0.x += a1.x; a0.y += a1.y; a0.z += a1.z; a0.w += a1.w;
#pragma unroll
    for (int m = 4; m < 64; m <<= 1) {
        a0.x += __shfl_xor(a0.x, m);
        a0.y += __shfl_xor(a0.y, m);
        a0.z += __shfl_xor(a0.z, m);
        a0.w += __shfl_xor(a0.w, m);
    }
    if (lane < 4) *(float4*)(esum + (size_t)v * 16 + fo) = a0;
    if (lane == 0) degf[v] = (float)(rp1 - rp0);
}

// Fold: WcT[t][j][k] = sum_m W_msg[t][k][m] * W_ih[t][j][m]   (j<192, k<144)
//       bvec[t][j]   = sum_m b_msg[t][m]    * W_ih[t][j][m]
__global__ __launch_bounds__(192) void fold_kernel(
        const float* __restrict__ W_msg, const float* __restrict__ b_msg,
        const float* __restrict__ W_ih, float* __restrict__ WcT,
        float* __restrict__ bvec) {
    __shared__ float ldsW[64][193];
    int t = blockIdx.x / 9;
    int k0 = (blockIdx.x % 9) * 16;
    int j = threadIdx.x;
    float acc[16];
#pragma unroll
    for (int kk = 0; kk < 16; ++kk) acc[kk] = 0.f;
    float bacc = 0.f;
    for (int mc = 0; mc < 2; ++mc) {
        for (int i = threadIdx.x; i < 192 * 64; i += 192) {
            int jj = i >> 6, mm = i & 63;
            ldsW[mm][jj] = W_ih[((size_t)t * 192 + jj) * 128 + mc * 64 + mm];
        }
        __syncthreads();
        for (int mm = 0; mm < 64; ++mm) {
            float wl = ldsW[mm][j];
            float bm = b_msg[t * 128 + mc * 64 + mm];
            bacc = fmaf(bm, wl, bacc);
#pragma unroll
            for (int kk = 0; kk < 16; ++kk) {
                float wm = W_msg[((size_t)t * 144 + k0 + kk) * 128 + mc * 64 + mm];
                acc[kk] = fmaf(wm, wl, acc[kk]);
            }
        }
        __syncthreads();
    }
#pragma unroll
    for (int kk = 0; kk < 16; ++kk)
        WcT[((size_t)t * 192 + j) * 144 + k0 + kk] = acc[kk];
    if (k0 == 0) bvec[t * 192 + j] = bacc;
}

// BTf[t][n][k] fp32, n<256, k<224, zero-padded; biases folded.
// A layout: [h(0:64) | S(64:128) | dgh(128:192) | esum(192:208) | deg(208) | 1(209) | 0pad]
__global__ void wbig_kernel(const float* __restrict__ WcT, const float* __restrict__ bvec,
                            const float* __restrict__ b_ih, const float* __restrict__ b_hh,
                            const float* __restrict__ W_hh,
                            float* __restrict__ BTf) {
    int idx = blockIdx.x * 256 + threadIdx.x;
    if (idx >= 2 * 256 * KAF) return;
    int t = idx / (256 * KAF);
    int rem = idx % (256 * KAF);
    int n = rem / KAF, k = rem % KAF;
    float v = 0.f;
    if (n < 192) {
        if (k < 64) {
            if (n < 128) v = W_hh[(size_t)t * 192 * 64 + n * 64 + k];
        } else if (k < 128) {
            v = WcT[((size_t)t * 192 + n) * 144 + k];
        } else if (k < 192) {
            v = WcT[((size_t)t * 192 + n) * 144 + (k - 128)];
        } else if (k < 208) {
            v = WcT[((size_t)t * 192 + n) * 144 + 128 + (k - 192)];
        } else if (k == 208) {
            v = bvec[t * 192 + n];
        } else if (k == 209) {
            v = (n < 128) ? (b_ih[t * 192 + n] + b_hh[t * 192 + n]) : b_ih[t * 192 + n];
        }
    } else {
        int j = n - 64;   // 128..191
        if (k < 64) v = W_hh[(size_t)t * 192 * 64 + j * 64 + k];
        else if (k == 209) v = b_hh[t * 192 + j];
    }
    BTf[idx] = v;
}

// round-invariant tail of A: [esum (16) | deg | 1 | zeros]
__global__ void atail_kernel(const float* __restrict__ esum, const float* __restrict__ degf,
                             float* __restrict__ A) {
    int i = blockIdx.x * blockDim.x + threadIdx.x;
    if (i >= NN * 32) return;
    int v = i >> 5, k = 192 + (i & 31);
    float val;
    if (k < 208) val = esum[(size_t)v * 16 + (k - 192)];
    else if (k == 208) val = degf[v];
    else if (k == 209) val = 1.f;
    else val = 0.f;
    A[(size_t)v * KAF + k] = val;
}

// ---------------- per-round ----------------
// A[v][0:192) = [ h (fp32 self) | S = sum_src h_f16 | deg*h ]
__global__ __launch_bounds__(256) void gather_kernel(
        const float* __restrict__ hv, const unsigned short* __restrict__ hf,
        const int* __restrict__ row_ptr, const int2* __restrict__ adj,
        float* __restrict__ A) {
    int wid = threadIdx.x >> 6, lane = threadIdx.x & 63;
    int v = blockIdx.x * 4 + wid;
    if (v >= NN) return;
    int rp0 = row_ptr[v], rp1 = row_ptr[v + 1];
    int q = lane >> 4;
    int fo = (lane & 15) << 2;           // 4 halfs (8B) per lane
    float4 acc[8];
#pragma unroll
    for (int u = 0; u < 8; ++u) acc[u] = make_float4(0.f, 0.f, 0.f, 0.f);
    int i = rp0 + q;
    for (; i + 28 < rp1; i += 32) {
        int s[8];
#pragma unroll
        for (int u = 0; u < 8; ++u) s[u] = adj[i + 4 * u].x;
#pragma unroll
        for (int u = 0; u < 8; ++u) {
            ushort4 x = *(const ushort4*)(hf + (size_t)s[u] * 64 + fo);
            acc[u].x += h2f(x.x); acc[u].y += h2f(x.y);
            acc[u].z += h2f(x.z); acc[u].w += h2f(x.w);
        }
    }
    for (; i + 4 < rp1; i += 8) {
        int s0 = adj[i].x, s1 = adj[i + 4].x;
        ushort4 x0 = *(const ushort4*)(hf + (size_t)s0 * 64 + fo);
        ushort4 x1 = *(const ushort4*)(hf + (size_t)s1 * 64 + fo);
        acc[0].x += h2f(x0.x); acc[0].y += h2f(x0.y);
        acc[0].z += h2f(x0.z); acc[0].w += h2f(x0.w);
        acc[1].x += h2f(x1.x); acc[1].y += h2f(x1.y);
        acc[1].z += h2f(x1.z); acc[1].w += h2f(x1.w);
    }
    for (; i < rp1; i += 4) {
        int s = adj[i].x;
        ushort4 x = *(const ushort4*)(hf + (size_t)s * 64 + fo);
        acc[0].x += h2f(x.x); acc[0].y += h2f(x.y);
        acc[0].z += h2f(x.z); acc[0].w += h2f(x.w);
    }
#pragma unroll
    for (int u = 1; u < 8; ++u) {
        acc[0].x += acc[u].x; acc[0].y += acc[u].y;
        acc[0].z += acc[u].z; acc[0].w += acc[u].w;
    }
#pragma unroll
    for (int m = 16; m < 64; m <<= 1) {
        acc[0].x += __shfl_xor(acc[0].x, m);
        acc[0].y += __shfl_xor(acc[0].y, m);
        acc[0].z += __shfl_xor(acc[0].z, m);
        acc[0].w += __shfl_xor(acc[0].w, m);
    }
    if (lane < 16) {
        float dg = (float)(rp1 - rp0);
        float4 hvv = *(const float4*)(hv + (size_t)v * 64 + fo);
        *(float4*)(A + (size_t)v * KAF + fo) = hvv;
        *(float4*)(A + (size_t)v * KAF + 64 + fo) = acc[0];
        *(float4*)(A + (size_t)v * KAF + 128 + fo) =
            make_float4(dg * hvv.x, dg * hvv.y, dg * hvv.z, dg * hvv.w);
    }
}

// Fused fp32 GEMM (64x256 tile, K=224) + GRU gates.
// Col groups: g0=[0,64) r, g1=[64,128) z, g2=[128,192) i_n, g3=[192,256) h_n.
// K phases (BRANCH-FREE inner loops — R9 post-mortem: conditionals inside the
// unrolled kk loop caused acc spills -> 460 MB scratch traffic):
//   ks 0-1: g0,g1,g3   (g2's B block is all-zero for k<64)
//   ks 2-5: g0,g1,g2   (g3 zero for 64<=k<192)
//   ks 6  : all 4      (bias columns 208/209)
__global__ __launch_bounds__(512) void gemm_gate(
        const float* __restrict__ A, const float* __restrict__ BTf,
        const float* __restrict__ hin,
        float* __restrict__ fout, unsigned short* __restrict__ hfout) {
    __shared__ float As[32][68];     // [k][row], +4 pad
    __shared__ float Bs[32][264];    // [k][n],  +8 pad
    int tid = threadIdx.x;
    int ty = tid >> 5, tx = tid & 31;        // rows ty*4..+4, col pair 2tx per group
    int row0 = blockIdx.x * 64;
    float acc0[4][2], acc1[4][2], acc2[4][2], acc3[4][2];
#pragma unroll
    for (int i = 0; i < 4; ++i) {
        acc0[i][0] = 0.f; acc0[i][1] = 0.f;
        acc1[i][0] = 0.f; acc1[i][1] = 0.f;
        acc2[i][0] = 0.f; acc2[i][1] = 0.f;
        acc3[i][0] = 0.f; acc3[i][1] = 0.f;
    }

    int lr = tid >> 3, lk = (tid & 7) * 4;   // A stage: row lr, k lk..+4
    int ln = tid >> 1, lkb = (tid & 1) * 16; // B stage: n ln, k lkb..+16

#define STAGE(K0) do {                                                        \
    float4 va = *(const float4*)(A + (size_t)(row0 + lr) * KAF + (K0) + lk);  \
    As[lk + 0][lr] = va.x; As[lk + 1][lr] = va.y;                             \
    As[lk + 2][lr] = va.z; As[lk + 3][lr] = va.w;                             \
    const float4* bp = (const float4*)(BTf + (size_t)ln * KAF + (K0) + lkb);  \
    float4 v0 = bp[0], v1 = bp[1], v2 = bp[2], v3 = bp[3];                    \
    Bs[lkb + 0][ln] = v0.x; Bs[lkb + 1][ln] = v0.y;                           \
    Bs[lkb + 2][ln] = v0.z; Bs[lkb + 3][ln] = v0.w;                           \
    Bs[lkb + 4][ln] = v1.x; Bs[lkb + 5][ln] = v1.y;                           \
    Bs[lkb + 6][ln] = v1.z; Bs[lkb + 7][ln] = v1.w;                           \
    Bs[lkb + 8][ln] = v2.x; Bs[lkb + 9][ln] = v2.y;                           \
    Bs[lkb + 10][ln] = v2.z; Bs[lkb + 11][ln] = v2.w;                         \
    Bs[lkb + 12][ln] = v3.x; Bs[lkb + 13][ln] = v3.y;                         \
    Bs[lkb + 14][ln] = v3.z; Bs[lkb + 15][ln] = v3.w;                         \
} while (0)

#define COMPUTE(DO2, DO3) do {                                                \
    _Pragma("unroll")                                                         \
    for (int kk = 0; kk < 32; ++kk) {                                         \
        float4 av = *(const float4*)&As[kk][ty * 4];                          \
        float a4[4] = {av.x, av.y, av.z, av.w};                               \
        float2 b0 = *(const float2*)&Bs[kk][2 * tx];                          \
        float2 b1 = *(const float2*)&Bs[kk][64 + 2 * tx];                     \
        _Pragma("unroll")                                                     \
        for (int i = 0; i < 4; ++i) {                                         \
            acc0[i][0] = fmaf(a4[i], b0.x, acc0[i][0]);                       \
            acc0[i][1] = fmaf(a4[i], b0.y, acc0[i][1]);                       \
            acc1[i][0] = fmaf(a4[i], b1.x, acc1[i][0]);                       \
            acc1[i][1] = fmaf(a4[i], b1.y, acc1[i][1]);                       \
        }                                                                     \
        if (DO2) {                                                            \
            float2 b2 = *(const float2*)&Bs[kk][128 + 2 * tx];                \
            _Pragma("unroll")                                                 \
            for (int i = 0; i < 4; ++i) {                                     \
                acc2[i][0] = fmaf(a4[i], b2.x, acc2[i][0]);                   \
                acc2[i][1] = fmaf(a4[i], b2.y, acc2[i][1]);                   \
            }                                                                 \
        }                                                                     \
        if (DO3) {                                                            \
            float2 b3 = *(const float2*)&Bs[kk][192 + 2 * tx];                \
            _Pragma("unroll")                                                 \
            for (int i = 0; i < 4; ++i) {                                     \
                acc3[i][0] = fmaf(a4[i], b3.x, acc3[i][0]);                   \
                acc3[i][1] = fmaf(a4[i], b3.y, acc3[i][1]);                   \
            }                                                                 \
        }                                                                     \
    }                                                                         \
} while (0)

#pragma unroll 1
    for (int ks = 0; ks < 2; ++ks) {
        STAGE(ks * 32);
        __syncthreads();
        COMPUTE(0, 1);
        __syncthreads();
    }
#pragma unroll 1
    for (int ks = 2; ks < 6; ++ks) {
        STAGE(ks * 32);
        __syncthreads();
        COMPUTE(1, 0);
        __syncthreads();
    }
    {
        STAGE(192);
        __syncthreads();
        COMPUTE(1, 1);
        __syncthreads();
    }
#undef STAGE
#undef COMPUTE

    // epilogue: GRU gates
#pragma unroll
    for (int i = 0; i < 4; ++i) {
        int row = row0 + ty * 4 + i;
        if (row >= NN) continue;
#pragma unroll
        for (int c = 0; c < 2; ++c) {
            int j = 2 * tx + c;
            float rr = acc0[i][c];
            float zz = acc1[i][c];
            float in_ = acc2[i][c];
            float hn = acc3[i][c];
            float r = 1.f / (1.f + __expf(-rr));
            float z = 1.f / (1.f + __expf(-zz));
            float n = tanhf(in_ + r * hn);
            float h = hin[(size_t)row * 64 + j];
            float val = (1.f - z) * n + z * h;
            fout[(size_t)row * 64 + j] = val;
            hfout[(size_t)row * 64 + j] = f2h(val);
        }
    }
}

extern "C" void kernel_launch(void* const* d_in, const int* in_sizes, int n_in,
                              void* d_out, int out_size, void* d_ws, size_t ws_size,
                              hipStream_t stream) {
    const float* hv0   = (const float*)d_in[0];
    const float* ef    = (const float*)d_in[1];
    const int*   src   = (const int*)d_in[2];
    const int*   dst   = (const int*)d_in[3];
    const float* W_msg = (const float*)d_in[4];
    const float* b_msg = (const float*)d_in[5];
    const float* W_ih  = (const float*)d_in[6];
    const float* W_hh  = (const float*)d_in[7];
    const float* b_ih  = (const float*)d_in[8];
    const float* b_hh  = (const float*)d_in[9];
    float* out = (float*)d_out;

    char* ws = (char*)d_ws;
    size_t off = 0;
    auto alloc = [&](size_t bytes) -> char* {
        char* p = ws + off;
        off = (off + bytes + 255) & ~(size_t)255;
        return p;
    };
    int*   cnt      = (int*)alloc((size_t)NC * NN * 4);
    int*   row_ptr  = (int*)alloc((NN + 1) * 4);
    int*   cursor   = (int*)alloc((size_t)NC * NN * 4);
    int2*  adj      = (int2*)alloc((size_t)NE * 8);
    float* esum     = (float*)alloc((size_t)NN * 16 * 4);
    float* degf     = (float*)alloc(NN * 4);
    float* WcT      = (float*)alloc((size_t)2 * 192 * 144 * 4);
    float* bvec     = (float*)alloc(2 * 192 * 4);
    int*   lp       = (int*)alloc(NN * 4);
    int*   bsum     = (int*)alloc(NB_SCAN * 4);
    int*   boff     = (int*)alloc(NB_SCAN * 4);
    float* A        = (float*)alloc((size_t)MP * KAF * 4);
    float* BTf      = (float*)alloc((size_t)2 * 256 * KAF * 4);
    float* hv1      = (float*)alloc((size_t)NN * 64 * 4);
    unsigned short* hf0 = (unsigned short*)alloc((size_t)NN * 64 * 2);
    unsigned short* hf1 = (unsigned short*)alloc((size_t)NN * 64 * 2);

    zero_kernel<<<(NC * NN + 1023) / 1024, 1024, 0, stream>>>(cnt, NC * NN);
    tohf_kernel<<<(NN * 64 + 255) / 256, 256, 0, stream>>>(hv0, hf0, NN * 64);
    hist_kernel<<<(NE + 255) / 256, 256, 0, stream>>>(dst, cnt);
    scan1_kernel<<<NB_SCAN, 256, 0, stream>>>(cnt, lp, bsum);
    scan2_kernel<<<1, 128, 0, stream>>>(bsum, boff);
    scan3_kernel<<<NB_SCAN, 256, 0, stream>>>(cnt, lp, boff, row_ptr, cursor);
    place_kernel<<<(NE + 255) / 256, 256, 0, stream>>>(src, dst, cursor, adj);
    esum_csr_kernel<<<(NN + 3) / 4, 256, 0, stream>>>(ef, row_ptr, adj, esum, degf);
    fold_kernel<<<18, 192, 0, stream>>>(W_msg, b_msg, W_ih, WcT, bvec);
    wbig_kernel<<<(2 * 256 * KAF + 255) / 256, 256, 0, stream>>>(WcT, bvec, b_ih, b_hh, W_hh, BTf);
    atail_kernel<<<(NN * 32 + 255) / 256, 256, 0, stream>>>(esum, degf, A);

    for (int t = 0; t < 2; ++t) {
        const float* hin = (t == 0) ? hv0 : hv1;
        const unsigned short* hfin = (t == 0) ? hf0 : hf1;
        float* hout = (t == 1) ? out : hv1;
        gather_kernel<<<(NN + 3) / 4, 256, 0, stream>>>(hin, hfin, row_ptr, adj, A);
        gemm_gate<<<MP / 64, 512, 0, stream>>>(A, BTf + (size_t)t * 256 * KAF,
                                               hin, hout, hf1);
    }
}

// Round 11
// 235.342 us; speedup vs baseline: 9.0636x; 1.4580x over previous
//
#include <hip/hip_runtime.h>
#include <cstddef>
#include <cstdint>

#define NN 20000
#define NE 640000
#define MP 20096       // padded rows (157*128)
#define KAF 224        // A row length (floats)
#define NC 8
#define CHUNK 80000    // NE / NC
#define NB_SCAN 79     // ceil(NN/256)

__device__ __forceinline__ float h2f(unsigned short u) {
    _Float16 h;
    *reinterpret_cast<unsigned short*>(&h) = u;
    return (float)h;
}
__device__ __forceinline__ unsigned short f2h(float f) {
    _Float16 h = (_Float16)f;
    return *reinterpret_cast<unsigned short*>(&h);
}

// ---------------- setup ----------------
__global__ void zero_kernel(int* __restrict__ p, int n) {
    int i = blockIdx.x * blockDim.x + threadIdx.x;
    if (i < n) p[i] = 0;
}

__global__ void tohf_kernel(const float* __restrict__ in, unsigned short* __restrict__ out, int n) {
    int i = blockIdx.x * blockDim.x + threadIdx.x;
    if (i < n) out[i] = f2h(in[i]);
}

__global__ void hist_kernel(const int* __restrict__ dst, int* __restrict__ cnt) {
    int i = blockIdx.x * blockDim.x + threadIdx.x;
    if (i < NE) atomicAdd(&cnt[(i / CHUNK) * NN + dst[i]], 1);
}

__global__ __launch_bounds__(256) void scan1_kernel(const int* __restrict__ cnt,
                                                    int* __restrict__ lp,
                                                    int* __restrict__ bsum) {
    __shared__ int s[256];
    int t = threadIdx.x;
    int i = blockIdx.x * 256 + t;
    int d = 0;
    if (i < NN)
#pragma unroll
        for (int c = 0; c < NC; ++c) d += cnt[c * NN + i];
    s[t] = d;
    __syncthreads();
    for (int off = 1; off < 256; off <<= 1) {
        int v = (t >= off) ? s[t - off] : 0;
        __syncthreads();
        s[t] += v;
        __syncthreads();
    }
    if (i < NN) lp[i] = s[t] - d;
    if (t == 255) bsum[blockIdx.x] = s[255];
}

__global__ __launch_bounds__(128) void scan2_kernel(const int* __restrict__ bsum,
                                                    int* __restrict__ boff) {
    __shared__ int s[128];
    int t = threadIdx.x;
    int v = (t < NB_SCAN) ? bsum[t] : 0;
    s[t] = v;
    __syncthreads();
    for (int off = 1; off < 128; off <<= 1) {
        int u = (t >= off) ? s[t - off] : 0;
        __syncthreads();
        s[t] += u;
        __syncthreads();
    }
    if (t < NB_SCAN) boff[t] = s[t] - v;
}

__global__ __launch_bounds__(256) void scan3_kernel(const int* __restrict__ cnt,
                                                    const int* __restrict__ lp,
                                                    const int* __restrict__ boff,
                                                    int* __restrict__ row_ptr,
                                                    int* __restrict__ cursor) {
    int i = blockIdx.x * 256 + threadIdx.x;
    if (i < NN) {
        int run = boff[blockIdx.x] + lp[i];
        row_ptr[i] = run;
#pragma unroll
        for (int c = 0; c < NC; ++c) {
            cursor[c * NN + i] = run;
            run += cnt[c * NN + i];
        }
    }
    if (i == 0) row_ptr[NN] = NE;
}

__global__ void place_kernel(const int* __restrict__ src, const int* __restrict__ dst,
                             int* __restrict__ cursor, int2* __restrict__ adj) {
    int i = blockIdx.x * blockDim.x + threadIdx.x;
    if (i < NE) {
        int d = dst[i];
        int pos = atomicAdd(&cursor[(i / CHUNK) * NN + d], 1);
        adj[pos] = make_int2(src[i], i);
    }
}

// esum[v] = sum of incoming-edge features (round-invariant); also degf.
__global__ __launch_bounds__(256) void esum_csr_kernel(
        const float* __restrict__ ef, const int* __restrict__ row_ptr,
        const int2* __restrict__ adj, float* __restrict__ esum,
        float* __restrict__ degf) {
    int wid = threadIdx.x >> 6, lane = threadIdx.x & 63;
    int v = blockIdx.x * 4 + wid;
    if (v >= NN) return;
    int rp0 = row_ptr[v], rp1 = row_ptr[v + 1];
    int q = lane >> 2;
    int fo = (lane & 3) << 2;
    float4 a0 = make_float4(0.f, 0.f, 0.f, 0.f), a1 = a0;
    int i = rp0 + q;
    for (; i + 16 < rp1; i += 32) {
        int e0 = adj[i].y, e1 = adj[i + 16].y;
        float4 x0 = *(const float4*)(ef + (size_t)e0 * 16 + fo);
        float4 x1 = *(const float4*)(ef + (size_t)e1 * 16 + fo);
        a0.x += x0.x; a0.y += x0.y; a0.z += x0.z; a0.w += x0.w;
        a1.x += x1.x; a1.y += x1.y; a1.z += x1.z; a1.w += x1.w;
    }
    for (; i < rp1; i += 16) {
        int e = adj[i].y;
        float4 x = *(const float4*)(ef + (size_t)e * 16 + fo);
        a0.x += x.x; a0.y += x.y; a0.z += x.z; a0.w += x.w;
    }
    a0.x += a1.x; a0.y += a1.y; a0.z += a1.z; a0.w += a1.w;
#pragma unroll
    for (int m = 4; m < 64; m <<= 1) {
        a0.x += __shfl_xor(a0.x, m);
        a0.y += __shfl_xor(a0.y, m);
        a0.z += __shfl_xor(a0.z, m);
        a0.w += __shfl_xor(a0.w, m);
    }
    if (lane < 4) *(float4*)(esum + (size_t)v * 16 + fo) = a0;
    if (lane == 0) degf[v] = (float)(rp1 - rp0);
}

// Fold: WcT[t][j][k] = sum_m W_msg[t][k][m] * W_ih[t][j][m]   (j<192, k<144)
//       bvec[t][j]   = sum_m b_msg[t][m]    * W_ih[t][j][m]
__global__ __launch_bounds__(192) void fold_kernel(
        const float* __restrict__ W_msg, const float* __restrict__ b_msg,
        const float* __restrict__ W_ih, float* __restrict__ WcT,
        float* __restrict__ bvec) {
    __shared__ float ldsW[64][193];
    int t = blockIdx.x / 9;
    int k0 = (blockIdx.x % 9) * 16;
    int j = threadIdx.x;
    float acc[16];
#pragma unroll
    for (int kk = 0; kk < 16; ++kk) acc[kk] = 0.f;
    float bacc = 0.f;
    for (int mc = 0; mc < 2; ++mc) {
        for (int i = threadIdx.x; i < 192 * 64; i += 192) {
            int jj = i >> 6, mm = i & 63;
            ldsW[mm][jj] = W_ih[((size_t)t * 192 + jj) * 128 + mc * 64 + mm];
        }
        __syncthreads();
        for (int mm = 0; mm < 64; ++mm) {
            float wl = ldsW[mm][j];
            float bm = b_msg[t * 128 + mc * 64 + mm];
            bacc = fmaf(bm, wl, bacc);
#pragma unroll
            for (int kk = 0; kk < 16; ++kk) {
                float wm = W_msg[((size_t)t * 144 + k0 + kk) * 128 + mc * 64 + mm];
                acc[kk] = fmaf(wm, wl, acc[kk]);
            }
        }
        __syncthreads();
    }
#pragma unroll
    for (int kk = 0; kk < 16; ++kk)
        WcT[((size_t)t * 192 + j) * 144 + k0 + kk] = acc[kk];
    if (k0 == 0) bvec[t * 192 + j] = bacc;
}

// BTf[t][n][k] fp32, n<256, k<224, zero-padded; biases folded.
// A layout: [h(0:64) | S(64:128) | dgh(128:192) | esum(192:208) | deg(208) | 1(209) | 0pad]
__global__ void wbig_kernel(const float* __restrict__ WcT, const float* __restrict__ bvec,
                            const float* __restrict__ b_ih, const float* __restrict__ b_hh,
                            const float* __restrict__ W_hh,
                            float* __restrict__ BTf) {
    int idx = blockIdx.x * 256 + threadIdx.x;
    if (idx >= 2 * 256 * KAF) return;
    int t = idx / (256 * KAF);
    int rem = idx % (256 * KAF);
    int n = rem / KAF, k = rem % KAF;
    float v = 0.f;
    if (n < 192) {
        if (k < 64) {
            if (n < 128) v = W_hh[(size_t)t * 192 * 64 + n * 64 + k];
        } else if (k < 128) {
            v = WcT[((size_t)t * 192 + n) * 144 + k];
        } else if (k < 192) {
            v = WcT[((size_t)t * 192 + n) * 144 + (k - 128)];
        } else if (k < 208) {
            v = WcT[((size_t)t * 192 + n) * 144 + 128 + (k - 192)];
        } else if (k == 208) {
            v = bvec[t * 192 + n];
        } else if (k == 209) {
            v = (n < 128) ? (b_ih[t * 192 + n] + b_hh[t * 192 + n]) : b_ih[t * 192 + n];
        }
    } else {
        int j = n - 64;   // 128..191
        if (k < 64) v = W_hh[(size_t)t * 192 * 64 + j * 64 + k];
        else if (k == 209) v = b_hh[t * 192 + j];
    }
    BTf[idx] = v;
}

// round-invariant tail of A: [esum (16) | deg | 1 | zeros]
__global__ void atail_kernel(const float* __restrict__ esum, const float* __restrict__ degf,
                             float* __restrict__ A) {
    int i = blockIdx.x * blockDim.x + threadIdx.x;
    if (i >= NN * 32) return;
    int v = i >> 5, k = 192 + (i & 31);
    float val;
    if (k < 208) val = esum[(size_t)v * 16 + (k - 192)];
    else if (k == 208) val = degf[v];
    else if (k == 209) val = 1.f;
    else val = 0.f;
    A[(size_t)v * KAF + k] = val;
}

// ---------------- per-round ----------------
// A[v][0:192) = [ h (fp32 self) | S = sum_src h_f16 | deg*h ]
__global__ __launch_bounds__(256) void gather_kernel(
        const float* __restrict__ hv, const unsigned short* __restrict__ hf,
        const int* __restrict__ row_ptr, const int2* __restrict__ adj,
        float* __restrict__ A) {
    int wid = threadIdx.x >> 6, lane = threadIdx.x & 63;
    int v = blockIdx.x * 4 + wid;
    if (v >= NN) return;
    int rp0 = row_ptr[v], rp1 = row_ptr[v + 1];
    int q = lane >> 4;
    int fo = (lane & 15) << 2;           // 4 halfs (8B) per lane
    float4 acc[8];
#pragma unroll
    for (int u = 0; u < 8; ++u) acc[u] = make_float4(0.f, 0.f, 0.f, 0.f);
    int i = rp0 + q;
    for (; i + 28 < rp1; i += 32) {
        int s[8];
#pragma unroll
        for (int u = 0; u < 8; ++u) s[u] = adj[i + 4 * u].x;
#pragma unroll
        for (int u = 0; u < 8; ++u) {
            ushort4 x = *(const ushort4*)(hf + (size_t)s[u] * 64 + fo);
            acc[u].x += h2f(x.x); acc[u].y += h2f(x.y);
            acc[u].z += h2f(x.z); acc[u].w += h2f(x.w);
        }
    }
    for (; i + 4 < rp1; i += 8) {
        int s0 = adj[i].x, s1 = adj[i + 4].x;
        ushort4 x0 = *(const ushort4*)(hf + (size_t)s0 * 64 + fo);
        ushort4 x1 = *(const ushort4*)(hf + (size_t)s1 * 64 + fo);
        acc[0].x += h2f(x0.x); acc[0].y += h2f(x0.y);
        acc[0].z += h2f(x0.z); acc[0].w += h2f(x0.w);
        acc[1].x += h2f(x1.x); acc[1].y += h2f(x1.y);
        acc[1].z += h2f(x1.z); acc[1].w += h2f(x1.w);
    }
    for (; i < rp1; i += 4) {
        int s = adj[i].x;
        ushort4 x = *(const ushort4*)(hf + (size_t)s * 64 + fo);
        acc[0].x += h2f(x.x); acc[0].y += h2f(x.y);
        acc[0].z += h2f(x.z); acc[0].w += h2f(x.w);
    }
#pragma unroll
    for (int u = 1; u < 8; ++u) {
        acc[0].x += acc[u].x; acc[0].y += acc[u].y;
        acc[0].z += acc[u].z; acc[0].w += acc[u].w;
    }
#pragma unroll
    for (int m = 16; m < 64; m <<= 1) {
        acc[0].x += __shfl_xor(acc[0].x, m);
        acc[0].y += __shfl_xor(acc[0].y, m);
        acc[0].z += __shfl_xor(acc[0].z, m);
        acc[0].w += __shfl_xor(acc[0].w, m);
    }
    if (lane < 16) {
        float dg = (float)(rp1 - rp0);
        float4 hvv = *(const float4*)(hv + (size_t)v * 64 + fo);
        *(float4*)(A + (size_t)v * KAF + fo) = hvv;
        *(float4*)(A + (size_t)v * KAF + 64 + fo) = acc[0];
        *(float4*)(A + (size_t)v * KAF + 128 + fo) =
            make_float4(dg * hvv.x, dg * hvv.y, dg * hvv.z, dg * hvv.w);
    }
}

// C[M,256] = A[M,224] @ BTf[256,224]^T — R6-proven shape: 256 thr, 128x64 tile,
// 8x4 acc, K as RUNTIME LOOP BOUNDS per col-group (no inner-loop branches, no
// 512-thread/40-acc shape — that spilled in R8-R10).
// by=0,1 (r,z):   k in [0,224)
// by=2   (i_n):   k in [64,224)   (B zero for k<64)
// by=3   (h_n):   k in [0,64) + [192,224)  (B zero in between)
__global__ __launch_bounds__(256) void gemm4(
    const float* __restrict__ A, const float* __restrict__ BTf,
    float* __restrict__ C) {
    const int BK = 32, NOUT = 256;
    __shared__ float As[32][132];
    __shared__ float Bs[32][68];
    int tid = threadIdx.x;
    int ty = tid >> 4, tx = tid & 15;
    int row0 = blockIdx.x * 128;
    int by = blockIdx.y;
    int col0 = by * 64;
    int lo1 = (by == 2) ? 64 : 0;
    int hi1 = (by == 3) ? 64 : 224;
    int lo2 = 192;
    int hi2 = (by == 3) ? 224 : 192;   // second range only for by==3
    float acc[8][4];
#pragma unroll
    for (int i = 0; i < 8; ++i)
#pragma unroll
        for (int j = 0; j < 4; ++j) acc[i][j] = 0.f;

    int lr = tid >> 3;
    int lk = (tid & 7) << 2;

#define STAGE(K0) do {                                                         \
    _Pragma("unroll")                                                          \
    for (int p = 0; p < 4; ++p) {                                              \
        int r = lr + p * 32;                                                   \
        float4 v = *(const float4*)(A + (size_t)(row0 + r) * KAF + (K0) + lk); \
        As[lk + 0][r] = v.x; As[lk + 1][r] = v.y;                              \
        As[lk + 2][r] = v.z; As[lk + 3][r] = v.w;                              \
    }                                                                          \
    _Pragma("unroll")                                                          \
    for (int p = 0; p < 2; ++p) {                                              \
        int n = lr + p * 32;                                                   \
        float4 v = *(const float4*)(BTf + (size_t)(col0 + n) * KAF + (K0) + lk); \
        Bs[lk + 0][n] = v.x; Bs[lk + 1][n] = v.y;                              \
        Bs[lk + 2][n] = v.z; Bs[lk + 3][n] = v.w;                              \
    }                                                                          \
} while (0)

#define COMP() do {                                                            \
    _Pragma("unroll")                                                          \
    for (int kk = 0; kk < BK; ++kk) {                                          \
        float4 a0 = *(const float4*)&As[kk][ty * 8];                           \
        float4 a1 = *(const float4*)&As[kk][ty * 8 + 4];                       \
        float4 b0 = *(const float4*)&Bs[kk][tx * 4];                           \
        float av[8] = {a0.x, a0.y, a0.z, a0.w, a1.x, a1.y, a1.z, a1.w};        \
        float bv[4] = {b0.x, b0.y, b0.z, b0.w};                                \
        _Pragma("unroll")                                                      \
        for (int i = 0; i < 8; ++i)                                            \
            _Pragma("unroll")                                                  \
            for (int j = 0; j < 4; ++j)                                        \
                acc[i][j] = fmaf(av[i], bv[j], acc[i][j]);                     \
    }                                                                          \
} while (0)

#pragma unroll 1
    for (int k0 = lo1; k0 < hi1; k0 += BK) {
        STAGE(k0);
        __syncthreads();
        COMP();
        __syncthreads();
    }
#pragma unroll 1
    for (int k0 = lo2; k0 < hi2; k0 += BK) {
        STAGE(k0);
        __syncthreads();
        COMP();
        __syncthreads();
    }
#undef STAGE
#undef COMP

    int c = col0 + tx * 4;
#pragma unroll
    for (int i = 0; i < 8; ++i) {
        int r = row0 + ty * 8 + i;
        if (r >= NN) continue;
        float4 o = make_float4(acc[i][0], acc[i][1], acc[i][2], acc[i][3]);
        *(float4*)(C + (size_t)r * NOUT + c) = o;
    }
}

// gates (all biases pre-folded into C): r=sig(c0), z=sig(c1), n=tanh(c2 + r*c3)
__global__ void gate_kernel(const float* __restrict__ C, const float* __restrict__ hin,
                            float* __restrict__ fout, unsigned short* __restrict__ hfout) {
    int idx = blockIdx.x * blockDim.x + threadIdx.x;
    if (idx >= NN * 64) return;
    int v = idx >> 6, j = idx & 63;
    const float* c = C + (size_t)v * 256;
    float r = 1.f / (1.f + __expf(-c[j]));
    float z = 1.f / (1.f + __expf(-c[64 + j]));
    float n = tanhf(c[128 + j] + r * c[192 + j]);
    float h = hin[idx];
    float val = (1.f - z) * n + z * h;
    fout[idx] = val;
    hfout[idx] = f2h(val);
}

extern "C" void kernel_launch(void* const* d_in, const int* in_sizes, int n_in,
                              void* d_out, int out_size, void* d_ws, size_t ws_size,
                              hipStream_t stream) {
    const float* hv0   = (const float*)d_in[0];
    const float* ef    = (const float*)d_in[1];
    const int*   src   = (const int*)d_in[2];
    const int*   dst   = (const int*)d_in[3];
    const float* W_msg = (const float*)d_in[4];
    const float* b_msg = (const float*)d_in[5];
    const float* W_ih  = (const float*)d_in[6];
    const float* W_hh  = (const float*)d_in[7];
    const float* b_ih  = (const float*)d_in[8];
    const float* b_hh  = (const float*)d_in[9];
    float* out = (float*)d_out;

    char* ws = (char*)d_ws;
    size_t off = 0;
    auto alloc = [&](size_t bytes) -> char* {
        char* p = ws + off;
        off = (off + bytes + 255) & ~(size_t)255;
        return p;
    };
    int*   cnt      = (int*)alloc((size_t)NC * NN * 4);
    int*   row_ptr  = (int*)alloc((NN + 1) * 4);
    int*   cursor   = (int*)alloc((size_t)NC * NN * 4);
    int2*  adj      = (int2*)alloc((size_t)NE * 8);
    float* esum     = (float*)alloc((size_t)NN * 16 * 4);
    float* degf     = (float*)alloc(NN * 4);
    float* WcT      = (float*)alloc((size_t)2 * 192 * 144 * 4);
    float* bvec     = (float*)alloc(2 * 192 * 4);
    int*   lp       = (int*)alloc(NN * 4);
    int*   bsum     = (int*)alloc(NB_SCAN * 4);
    int*   boff     = (int*)alloc(NB_SCAN * 4);
    float* A        = (float*)alloc((size_t)MP * KAF * 4);
    float* BTf      = (float*)alloc((size_t)2 * 256 * KAF * 4);
    float* Cbuf     = (float*)alloc((size_t)NN * 256 * 4);
    float* hv1      = (float*)alloc((size_t)NN * 64 * 4);
    unsigned short* hf0 = (unsigned short*)alloc((size_t)NN * 64 * 2);
    unsigned short* hf1 = (unsigned short*)alloc((size_t)NN * 64 * 2);

    zero_kernel<<<(NC * NN + 1023) / 1024, 1024, 0, stream>>>(cnt, NC * NN);
    tohf_kernel<<<(NN * 64 + 255) / 256, 256, 0, stream>>>(hv0, hf0, NN * 64);
    hist_kernel<<<(NE + 255) / 256, 256, 0, stream>>>(dst, cnt);
    scan1_kernel<<<NB_SCAN, 256, 0, stream>>>(cnt, lp, bsum);
    scan2_kernel<<<1, 128, 0, stream>>>(bsum, boff);
    scan3_kernel<<<NB_SCAN, 256, 0, stream>>>(cnt, lp, boff, row_ptr, cursor);
    place_kernel<<<(NE + 255) / 256, 256, 0, stream>>>(src, dst, cursor, adj);
    esum_csr_kernel<<<(NN + 3) / 4, 256, 0, stream>>>(ef, row_ptr, adj, esum, degf);
    fold_kernel<<<18, 192, 0, stream>>>(W_msg, b_msg, W_ih, WcT, bvec);
    wbig_kernel<<<(2 * 256 * KAF + 255) / 256, 256, 0, stream>>>(WcT, bvec, b_ih, b_hh, W_hh, BTf);
    atail_kernel<<<(NN * 32 + 255) / 256, 256, 0, stream>>>(esum, degf, A);

    for (int t = 0; t < 2; ++t) {
        const float* hin = (t == 0) ? hv0 : hv1;
        const unsigned short* hfin = (t == 0) ? hf0 : hf1;
        float* hout = (t == 1) ? out : hv1;
        gather_kernel<<<(NN + 3) / 4, 256, 0, stream>>>(hin, hfin, row_ptr, adj, A);
        dim3 gg(MP / 128, 4);
        gemm4<<<gg, 256, 0, stream>>>(A, BTf + (size_t)t * 256 * KAF, Cbuf);
        gate_kernel<<<(NN * 64 + 255) / 256, 256, 0, stream>>>(Cbuf, hin, hout, hf1);
    }
}

// Round 12
// 213.294 us; speedup vs baseline: 10.0004x; 1.1034x over previous
//
#include <hip/hip_runtime.h>
#include <cstddef>
#include <cstdint>

#define NN 20000
#define NE 640000
#define MP 20096       // padded rows (157*128)
#define KA 224         // A row length (halfs)
#define NC 8
#define CHUNK 80000    // NE / NC
#define NB_SCAN 79     // ceil(NN/256)

typedef _Float16 f16x8 __attribute__((ext_vector_type(8)));
typedef float f32x4 __attribute__((ext_vector_type(4)));

__device__ __forceinline__ float h2f(unsigned short u) {
    _Float16 h;
    *reinterpret_cast<unsigned short*>(&h) = u;
    return (float)h;
}
__device__ __forceinline__ unsigned short f2h(float f) {
    _Float16 h = (_Float16)f;
    return *reinterpret_cast<unsigned short*>(&h);
}
// fp16 two-term split: x ~= hi + lo (22 effective mantissa bits)
__device__ __forceinline__ void splitf(float x, unsigned short& hi, unsigned short& lo) {
    _Float16 h = (_Float16)x;
    _Float16 l = (_Float16)(x - (float)h);
    hi = *reinterpret_cast<unsigned short*>(&h);
    lo = *reinterpret_cast<unsigned short*>(&l);
}

// ---------------- setup ----------------
__global__ void zero_kernel(int* __restrict__ p, int n) {
    int i = blockIdx.x * blockDim.x + threadIdx.x;
    if (i < n) p[i] = 0;
}

__global__ void tohf_kernel(const float* __restrict__ in, unsigned short* __restrict__ out, int n) {
    int i = blockIdx.x * blockDim.x + threadIdx.x;
    if (i < n) out[i] = f2h(in[i]);
}

__global__ void hist_kernel(const int* __restrict__ dst, int* __restrict__ cnt) {
    int i = blockIdx.x * blockDim.x + threadIdx.x;
    if (i < NE) atomicAdd(&cnt[(i / CHUNK) * NN + dst[i]], 1);
}

__global__ __launch_bounds__(256) void scan1_kernel(const int* __restrict__ cnt,
                                                    int* __restrict__ lp,
                                                    int* __restrict__ bsum) {
    __shared__ int s[256];
    int t = threadIdx.x;
    int i = blockIdx.x * 256 + t;
    int d = 0;
    if (i < NN)
#pragma unroll
        for (int c = 0; c < NC; ++c) d += cnt[c * NN + i];
    s[t] = d;
    __syncthreads();
    for (int off = 1; off < 256; off <<= 1) {
        int v = (t >= off) ? s[t - off] : 0;
        __syncthreads();
        s[t] += v;
        __syncthreads();
    }
    if (i < NN) lp[i] = s[t] - d;
    if (t == 255) bsum[blockIdx.x] = s[255];
}

__global__ __launch_bounds__(128) void scan2_kernel(const int* __restrict__ bsum,
                                                    int* __restrict__ boff) {
    __shared__ int s[128];
    int t = threadIdx.x;
    int v = (t < NB_SCAN) ? bsum[t] : 0;
    s[t] = v;
    __syncthreads();
    for (int off = 1; off < 128; off <<= 1) {
        int u = (t >= off) ? s[t - off] : 0;
        __syncthreads();
        s[t] += u;
        __syncthreads();
    }
    if (t < NB_SCAN) boff[t] = s[t] - v;
}

__global__ __launch_bounds__(256) void scan3_kernel(const int* __restrict__ cnt,
                                                    const int* __restrict__ lp,
                                                    const int* __restrict__ boff,
                                                    int* __restrict__ row_ptr,
                                                    int* __restrict__ cursor) {
    int i = blockIdx.x * 256 + threadIdx.x;
    if (i < NN) {
        int run = boff[blockIdx.x] + lp[i];
        row_ptr[i] = run;
#pragma unroll
        for (int c = 0; c < NC; ++c) {
            cursor[c * NN + i] = run;
            run += cnt[c * NN + i];
        }
    }
    if (i == 0) row_ptr[NN] = NE;
}

__global__ void place_kernel(const int* __restrict__ src, const int* __restrict__ dst,
                             int* __restrict__ cursor, int2* __restrict__ adj) {
    int i = blockIdx.x * blockDim.x + threadIdx.x;
    if (i < NE) {
        int d = dst[i];
        int pos = atomicAdd(&cursor[(i / CHUNK) * NN + d], 1);
        adj[pos] = make_int2(src[i], i);
    }
}

// esum[v] = sum of incoming-edge features (round-invariant); also degf.
__global__ __launch_bounds__(256) void esum_csr_kernel(
        const float* __restrict__ ef, const int* __restrict__ row_ptr,
        const int2* __restrict__ adj, float* __restrict__ esum,
        float* __restrict__ degf) {
    int wid = threadIdx.x >> 6, lane = threadIdx.x & 63;
    int v = blockIdx.x * 4 + wid;
    if (v >= NN) return;
    int rp0 = row_ptr[v], rp1 = row_ptr[v + 1];
    int q = lane >> 2;
    int fo = (lane & 3) << 2;
    float4 a0 = make_float4(0.f, 0.f, 0.f, 0.f), a1 = a0;
    int i = rp0 + q;
    for (; i + 16 < rp1; i += 32) {
        int e0 = adj[i].y, e1 = adj[i + 16].y;
        float4 x0 = *(const float4*)(ef + (size_t)e0 * 16 + fo);
        float4 x1 = *(const float4*)(ef + (size_t)e1 * 16 + fo);
        a0.x += x0.x; a0.y += x0.y; a0.z += x0.z; a0.w += x0.w;
        a1.x += x1.x; a1.y += x1.y; a1.z += x1.z; a1.w += x1.w;
    }
    for (; i < rp1; i += 16) {
        int e = adj[i].y;
        float4 x = *(const float4*)(ef + (size_t)e * 16 + fo);
        a0.x += x.x; a0.y += x.y; a0.z += x.z; a0.w += x.w;
    }
    a0.x += a1.x; a0.y += a1.y; a0.z += a1.z; a0.w += a1.w;
#pragma unroll
    for (int m = 4; m < 64; m <<= 1) {
        a0.x += __shfl_xor(a0.x, m);
        a0.y += __shfl_xor(a0.y, m);
        a0.z += __shfl_xor(a0.z, m);
        a0.w += __shfl_xor(a0.w, m);
    }
    if (lane < 4) *(float4*)(esum + (size_t)v * 16 + fo) = a0;
    if (lane == 0) degf[v] = (float)(rp1 - rp0);
}

// Fold: WcT[t][j][k] = sum_m W_msg[t][k][m] * W_ih[t][j][m]   (j<192, k<144)
//       bvec[t][j]   = sum_m b_msg[t][m]    * W_ih[t][j][m]
__global__ __launch_bounds__(192) void fold_kernel(
        const float* __restrict__ W_msg, const float* __restrict__ b_msg,
        const float* __restrict__ W_ih, float* __restrict__ WcT,
        float* __restrict__ bvec) {
    __shared__ float ldsW[64][193];
    int t = blockIdx.x / 9;
    int k0 = (blockIdx.x % 9) * 16;
    int j = threadIdx.x;
    float acc[16];
#pragma unroll
    for (int kk = 0; kk < 16; ++kk) acc[kk] = 0.f;
    float bacc = 0.f;
    for (int mc = 0; mc < 2; ++mc) {
        for (int i = threadIdx.x; i < 192 * 64; i += 192) {
            int jj = i >> 6, mm = i & 63;
            ldsW[mm][jj] = W_ih[((size_t)t * 192 + jj) * 128 + mc * 64 + mm];
        }
        __syncthreads();
        for (int mm = 0; mm < 64; ++mm) {
            float wl = ldsW[mm][j];
            float bm = b_msg[t * 128 + mc * 64 + mm];
            bacc = fmaf(bm, wl, bacc);
#pragma unroll
            for (int kk = 0; kk < 16; ++kk) {
                float wm = W_msg[((size_t)t * 144 + k0 + kk) * 128 + mc * 64 + mm];
                acc[kk] = fmaf(wm, wl, acc[kk]);
            }
        }
        __syncthreads();
    }
#pragma unroll
    for (int kk = 0; kk < 16; ++kk)
        WcT[((size_t)t * 192 + j) * 144 + k0 + kk] = acc[kk];
    if (k0 == 0) bvec[t * 192 + j] = bacc;
}

// B[t][n][k] (n<256, k<224), zero-padded, biases folded — same algebra as R11
// (proven absmax 0.03125), now emitted as fp16 hi/lo pair.
// A layout: [h(0:64) | S(64:128) | dgh(128:192) | esum(192:208) | deg(208) | 1(209) | 0pad]
__global__ void wbig_kernel(const float* __restrict__ WcT, const float* __restrict__ bvec,
                            const float* __restrict__ b_ih, const float* __restrict__ b_hh,
                            const float* __restrict__ W_hh,
                            unsigned short* __restrict__ Bhi, unsigned short* __restrict__ Blo) {
    int idx = blockIdx.x * 256 + threadIdx.x;
    if (idx >= 2 * 256 * KA) return;
    int t = idx / (256 * KA);
    int rem = idx % (256 * KA);
    int n = rem / KA, k = rem % KA;
    float v = 0.f;
    if (n < 192) {
        if (k < 64) {
            if (n < 128) v = W_hh[(size_t)t * 192 * 64 + n * 64 + k];
        } else if (k < 128) {
            v = WcT[((size_t)t * 192 + n) * 144 + k];
        } else if (k < 192) {
            v = WcT[((size_t)t * 192 + n) * 144 + (k - 128)];
        } else if (k < 208) {
            v = WcT[((size_t)t * 192 + n) * 144 + 128 + (k - 192)];
        } else if (k == 208) {
            v = bvec[t * 192 + n];
        } else if (k == 209) {
            v = (n < 128) ? (b_ih[t * 192 + n] + b_hh[t * 192 + n]) : b_ih[t * 192 + n];
        }
    } else {
        int j = n - 64;   // 128..191
        if (k < 64) v = W_hh[(size_t)t * 192 * 64 + j * 64 + k];
        else if (k == 209) v = b_hh[t * 192 + j];
    }
    unsigned short hi, lo;
    splitf(v, hi, lo);
    Bhi[idx] = hi;
    Blo[idx] = lo;
}

// round-invariant tail of A: [esum (16) | deg | 1 | zeros], hi/lo
__global__ void atail_kernel(const float* __restrict__ esum, const float* __restrict__ degf,
                             unsigned short* __restrict__ Ahi, unsigned short* __restrict__ Alo) {
    int i = blockIdx.x * blockDim.x + threadIdx.x;
    if (i >= NN * 32) return;
    int v = i >> 5, k = 192 + (i & 31);
    float val;
    if (k < 208) val = esum[(size_t)v * 16 + (k - 192)];
    else if (k == 208) val = degf[v];
    else if (k == 209) val = 1.f;
    else val = 0.f;
    unsigned short hi, lo;
    splitf(val, hi, lo);
    Ahi[(size_t)v * KA + k] = hi;
    Alo[(size_t)v * KA + k] = lo;
}

// ---------------- per-round ----------------
// A[v][0:192) = [ h | S = sum_src h_f16 | deg*h ], written as fp16 hi/lo pair.
__global__ __launch_bounds__(256) void gather_kernel(
        const float* __restrict__ hv, const unsigned short* __restrict__ hf,
        const int* __restrict__ row_ptr, const int2* __restrict__ adj,
        unsigned short* __restrict__ Ahi, unsigned short* __restrict__ Alo) {
    int wid = threadIdx.x >> 6, lane = threadIdx.x & 63;
    int v = blockIdx.x * 4 + wid;
    if (v >= NN) return;
    int rp0 = row_ptr[v], rp1 = row_ptr[v + 1];
    int q = lane >> 4;
    int fo = (lane & 15) << 2;           // 4 halfs (8B) per lane
    float4 acc[8];
#pragma unroll
    for (int u = 0; u < 8; ++u) acc[u] = make_float4(0.f, 0.f, 0.f, 0.f);
    int i = rp0 + q;
    for (; i + 28 < rp1; i += 32) {
        int s[8];
#pragma unroll
        for (int u = 0; u < 8; ++u) s[u] = adj[i + 4 * u].x;
#pragma unroll
        for (int u = 0; u < 8; ++u) {
            ushort4 x = *(const ushort4*)(hf + (size_t)s[u] * 64 + fo);
            acc[u].x += h2f(x.x); acc[u].y += h2f(x.y);
            acc[u].z += h2f(x.z); acc[u].w += h2f(x.w);
        }
    }
    for (; i + 4 < rp1; i += 8) {
        int s0 = adj[i].x, s1 = adj[i + 4].x;
        ushort4 x0 = *(const ushort4*)(hf + (size_t)s0 * 64 + fo);
        ushort4 x1 = *(const ushort4*)(hf + (size_t)s1 * 64 + fo);
        acc[0].x += h2f(x0.x); acc[0].y += h2f(x0.y);
        acc[0].z += h2f(x0.z); acc[0].w += h2f(x0.w);
        acc[1].x += h2f(x1.x); acc[1].y += h2f(x1.y);
        acc[1].z += h2f(x1.z); acc[1].w += h2f(x1.w);
    }
    for (; i < rp1; i += 4) {
        int s = adj[i].x;
        ushort4 x = *(const ushort4*)(hf + (size_t)s * 64 + fo);
        acc[0].x += h2f(x.x); acc[0].y += h2f(x.y);
        acc[0].z += h2f(x.z); acc[0].w += h2f(x.w);
    }
#pragma unroll
    for (int u = 1; u < 8; ++u) {
        acc[0].x += acc[u].x; acc[0].y += acc[u].y;
        acc[0].z += acc[u].z; acc[0].w += acc[u].w;
    }
#pragma unroll
    for (int m = 16; m < 64; m <<= 1) {
        acc[0].x += __shfl_xor(acc[0].x, m);
        acc[0].y += __shfl_xor(acc[0].y, m);
        acc[0].z += __shfl_xor(acc[0].z, m);
        acc[0].w += __shfl_xor(acc[0].w, m);
    }
    if (lane < 16) {
        float dg = (float)(rp1 - rp0);
        float4 hvv = *(const float4*)(hv + (size_t)v * 64 + fo);
        float4 dv = make_float4(dg * hvv.x, dg * hvv.y, dg * hvv.z, dg * hvv.w);
        ushort4 hh, hl, sh, sl, dh, dl;
        splitf(hvv.x, hh.x, hl.x); splitf(hvv.y, hh.y, hl.y);
        splitf(hvv.z, hh.z, hl.z); splitf(hvv.w, hh.w, hl.w);
        splitf(acc[0].x, sh.x, sl.x); splitf(acc[0].y, sh.y, sl.y);
        splitf(acc[0].z, sh.z, sl.z); splitf(acc[0].w, sh.w, sl.w);
        splitf(dv.x, dh.x, dl.x); splitf(dv.y, dh.y, dl.y);
        splitf(dv.z, dh.z, dl.z); splitf(dv.w, dh.w, dl.w);
        *(ushort4*)(Ahi + (size_t)v * KA + fo) = hh;
        *(ushort4*)(Alo + (size_t)v * KA + fo) = hl;
        *(ushort4*)(Ahi + (size_t)v * KA + 64 + fo) = sh;
        *(ushort4*)(Alo + (size_t)v * KA + 64 + fo) = sl;
        *(ushort4*)(Ahi + (size_t)v * KA + 128 + fo) = dh;
        *(ushort4*)(Alo + (size_t)v * KA + 128 + fo) = dl;
    }
}

// Fused MFMA GEMM (128x256 tile, K=224) + in-register GRU gates.
// fp16 two-term split: C = Ahi*Bhi + Ahi*Blo + Alo*Bhi  (~fp32 precision).
// Fragment indexing verified by R7 execution (0.407 = quant-scale error, not
// layout-garbage). ks loop NOT unrolled (R8 spill lesson).
__global__ __launch_bounds__(512) void gemm_gru(
        const _Float16* __restrict__ Ahi, const _Float16* __restrict__ Alo,
        const _Float16* __restrict__ Bhi, const _Float16* __restrict__ Blo,
        const float* __restrict__ hin,
        float* __restrict__ fout, unsigned short* __restrict__ hfout) {
    __shared__ _Float16 Ash[128][40];   // +8 pad
    __shared__ _Float16 Asl[128][40];
    __shared__ _Float16 Bsh[256][40];
    __shared__ _Float16 Bsl[256][40];
    int tid = threadIdx.x;
    int w = tid >> 6, l = tid & 63;
    int row0 = blockIdx.x * 128;
    f32x4 acc[16];
#pragma unroll
    for (int i = 0; i < 16; ++i) acc[i] = (f32x4){0.f, 0.f, 0.f, 0.f};

#pragma unroll 1
    for (int ks = 0; ks < 7; ++ks) {
        int k0 = ks * 32;
        {   // stage A hi/lo: 128 rows x 32 halfs each
            int r = tid >> 2, c = (tid & 3) * 8;
            *(float4*)&Ash[r][c] = *(const float4*)(Ahi + (size_t)(row0 + r) * KA + k0 + c);
            *(float4*)&Asl[r][c] = *(const float4*)(Alo + (size_t)(row0 + r) * KA + k0 + c);
        }
        {   // stage B hi/lo: 256 rows x 32 halfs each
            int n = tid >> 1, c = (tid & 1) * 16;
            const float4* ph = (const float4*)(Bhi + (size_t)n * KA + k0 + c);
            float4 h0 = ph[0], h1 = ph[1];
            *(float4*)&Bsh[n][c] = h0;
            *(float4*)&Bsh[n][c + 8] = h1;
            const float4* pl = (const float4*)(Blo + (size_t)n * KA + k0 + c);
            float4 l0 = pl[0], l1 = pl[1];
            *(float4*)&Bsl[n][c] = l0;
            *(float4*)&Bsl[n][c + 8] = l1;
        }
        __syncthreads();
        int kg = (l >> 4) * 8;
        int ar = w * 16 + (l & 15);
        f16x8 ah = *(const f16x8*)&Ash[ar][kg];
        f16x8 al = *(const f16x8*)&Asl[ar][kg];
#pragma unroll
        for (int fn = 0; fn < 16; ++fn) {
            f16x8 bh = *(const f16x8*)&Bsh[fn * 16 + (l & 15)][kg];
            f16x8 bl = *(const f16x8*)&Bsl[fn * 16 + (l & 15)][kg];
            acc[fn] = __builtin_amdgcn_mfma_f32_16x16x32_f16(ah, bh, acc[fn], 0, 0, 0);
            acc[fn] = __builtin_amdgcn_mfma_f32_16x16x32_f16(ah, bl, acc[fn], 0, 0, 0);
            acc[fn] = __builtin_amdgcn_mfma_f32_16x16x32_f16(al, bh, acc[fn], 0, 0, 0);
        }
        __syncthreads();
    }

    // epilogue: lane l, reg q -> row = w*16 + (l>>4)*4 + q; col j = (l&15)+16*fj
    // acc[fj]=r, acc[4+fj]=z, acc[8+fj]=i_n, acc[12+fj]=h_n (biases pre-folded)
    int jb = l & 15;
#pragma unroll
    for (int q = 0; q < 4; ++q) {
        int row = row0 + w * 16 + (l >> 4) * 4 + q;
        if (row >= NN) continue;
#pragma unroll
        for (int fj = 0; fj < 4; ++fj) {
            int j = jb + fj * 16;
            float rr = acc[fj][q];
            float zz = acc[4 + fj][q];
            float in_ = acc[8 + fj][q];
            float hn = acc[12 + fj][q];
            float r = 1.f / (1.f + __expf(-rr));
            float z = 1.f / (1.f + __expf(-zz));
            float n = tanhf(in_ + r * hn);
            float h = hin[(size_t)row * 64 + j];
            float val = (1.f - z) * n + z * h;
            fout[(size_t)row * 64 + j] = val;
            hfout[(size_t)row * 64 + j] = f2h(val);
        }
    }
}

extern "C" void kernel_launch(void* const* d_in, const int* in_sizes, int n_in,
                              void* d_out, int out_size, void* d_ws, size_t ws_size,
                              hipStream_t stream) {
    const float* hv0   = (const float*)d_in[0];
    const float* ef    = (const float*)d_in[1];
    const int*   src   = (const int*)d_in[2];
    const int*   dst   = (const int*)d_in[3];
    const float* W_msg = (const float*)d_in[4];
    const float* b_msg = (const float*)d_in[5];
    const float* W_ih  = (const float*)d_in[6];
    const float* W_hh  = (const float*)d_in[7];
    const float* b_ih  = (const float*)d_in[8];
    const float* b_hh  = (const float*)d_in[9];
    float* out = (float*)d_out;

    char* ws = (char*)d_ws;
    size_t off = 0;
    auto alloc = [&](size_t bytes) -> char* {
        char* p = ws + off;
        off = (off + bytes + 255) & ~(size_t)255;
        return p;
    };
    int*   cnt      = (int*)alloc((size_t)NC * NN * 4);
    int*   row_ptr  = (int*)alloc((NN + 1) * 4);
    int*   cursor   = (int*)alloc((size_t)NC * NN * 4);
    int2*  adj      = (int2*)alloc((size_t)NE * 8);
    float* esum     = (float*)alloc((size_t)NN * 16 * 4);
    float* degf     = (float*)alloc(NN * 4);
    float* WcT      = (float*)alloc((size_t)2 * 192 * 144 * 4);
    float* bvec     = (float*)alloc(2 * 192 * 4);
    int*   lp       = (int*)alloc(NN * 4);
    int*   bsum     = (int*)alloc(NB_SCAN * 4);
    int*   boff     = (int*)alloc(NB_SCAN * 4);
    unsigned short* Ahi = (unsigned short*)alloc((size_t)MP * KA * 2);
    unsigned short* Alo = (unsigned short*)alloc((size_t)MP * KA * 2);
    unsigned short* Bhi = (unsigned short*)alloc((size_t)2 * 256 * KA * 2);
    unsigned short* Blo = (unsigned short*)alloc((size_t)2 * 256 * KA * 2);
    float* hv1      = (float*)alloc((size_t)NN * 64 * 4);
    unsigned short* hf0 = (unsigned short*)alloc((size_t)NN * 64 * 2);
    unsigned short* hf1 = (unsigned short*)alloc((size_t)NN * 64 * 2);

    zero_kernel<<<(NC * NN + 1023) / 1024, 1024, 0, stream>>>(cnt, NC * NN);
    tohf_kernel<<<(NN * 64 + 255) / 256, 256, 0, stream>>>(hv0, hf0, NN * 64);
    hist_kernel<<<(NE + 255) / 256, 256, 0, stream>>>(dst, cnt);
    scan1_kernel<<<NB_SCAN, 256, 0, stream>>>(cnt, lp, bsum);
    scan2_kernel<<<1, 128, 0, stream>>>(bsum, boff);
    scan3_kernel<<<NB_SCAN, 256, 0, stream>>>(cnt, lp, boff, row_ptr, cursor);
    place_kernel<<<(NE + 255) / 256, 256, 0, stream>>>(src, dst, cursor, adj);
    esum_csr_kernel<<<(NN + 3) / 4, 256, 0, stream>>>(ef, row_ptr, adj, esum, degf);
    fold_kernel<<<18, 192, 0, stream>>>(W_msg, b_msg, W_ih, WcT, bvec);
    wbig_kernel<<<(2 * 256 * KA + 255) / 256, 256, 0, stream>>>(WcT, bvec, b_ih, b_hh,
                                                                W_hh, Bhi, Blo);
    atail_kernel<<<(NN * 32 + 255) / 256, 256, 0, stream>>>(esum, degf, Ahi, Alo);

    for (int t = 0; t < 2; ++t) {
        const float* hin = (t == 0) ? hv0 : hv1;
        const unsigned short* hfin = (t == 0) ? hf0 : hf1;
        float* hout = (t == 1) ? out : hv1;
        gather_kernel<<<(NN + 3) / 4, 256, 0, stream>>>(hin, hfin, row_ptr, adj, Ahi, Alo);
        gemm_gru<<<MP / 128, 512, 0, stream>>>(
            (const _Float16*)Ahi, (const _Float16*)Alo,
            (const _Float16*)(Bhi + (size_t)t * 256 * KA),
            (const _Float16*)(Blo + (size_t)t * 256 * KA),
            hin, hout, hf1);
    }
}

// Round 13
// 207.096 us; speedup vs baseline: 10.2998x; 1.0299x over previous
//
#include <hip/hip_runtime.h>
#include <cstddef>
#include <cstdint>

#define NN 20000
#define NE 640000
#define MP 20096       // padded rows (314*64)
#define KA 224         // A row length (halfs)
#define NC 16
#define CHUNK 40000    // NE / NC
#define NB_SCAN 79     // ceil(NN/256)

typedef _Float16 f16x8 __attribute__((ext_vector_type(8)));
typedef float f32x4 __attribute__((ext_vector_type(4)));

__device__ __forceinline__ float h2f(unsigned short u) {
    _Float16 h;
    *reinterpret_cast<unsigned short*>(&h) = u;
    return (float)h;
}
__device__ __forceinline__ unsigned short f2h(float f) {
    _Float16 h = (_Float16)f;
    return *reinterpret_cast<unsigned short*>(&h);
}
// fp16 two-term split: x ~= hi + lo (22 effective mantissa bits)
__device__ __forceinline__ void splitf(float x, unsigned short& hi, unsigned short& lo) {
    _Float16 h = (_Float16)x;
    _Float16 l = (_Float16)(x - (float)h);
    hi = *reinterpret_cast<unsigned short*>(&h);
    lo = *reinterpret_cast<unsigned short*>(&l);
}

// ---------------- setup ----------------
// merged: zero cnt + fp16 table build (saves one launch)
__global__ void init_kernel(const float* __restrict__ hv0, unsigned short* __restrict__ hf0,
                            int* __restrict__ cnt) {
    int i = blockIdx.x * blockDim.x + threadIdx.x;
    if (i < NC * NN) cnt[i] = 0;
    if (i < NN * 64) hf0[i] = f2h(hv0[i]);
}

__global__ void hist_kernel(const int* __restrict__ dst, int* __restrict__ cnt) {
    int i = blockIdx.x * blockDim.x + threadIdx.x;
    if (i < NE) atomicAdd(&cnt[(i / CHUNK) * NN + dst[i]], 1);
}

__global__ __launch_bounds__(256) void scan1_kernel(const int* __restrict__ cnt,
                                                    int* __restrict__ lp,
                                                    int* __restrict__ bsum) {
    __shared__ int s[256];
    int t = threadIdx.x;
    int i = blockIdx.x * 256 + t;
    int d = 0;
    if (i < NN)
#pragma unroll
        for (int c = 0; c < NC; ++c) d += cnt[c * NN + i];
    s[t] = d;
    __syncthreads();
    for (int off = 1; off < 256; off <<= 1) {
        int v = (t >= off) ? s[t - off] : 0;
        __syncthreads();
        s[t] += v;
        __syncthreads();
    }
    if (i < NN) lp[i] = s[t] - d;
    if (t == 255) bsum[blockIdx.x] = s[255];
}

// scan2 merged in: each block re-scans the 79 block sums (trivial), then emits
// row_ptr and the NC chunk cursors.
__global__ __launch_bounds__(256) void scan3_kernel(const int* __restrict__ cnt,
                                                    const int* __restrict__ lp,
                                                    const int* __restrict__ bsum,
                                                    int* __restrict__ row_ptr,
                                                    int* __restrict__ cursor) {
    __shared__ int sb[128];
    int t = threadIdx.x;
    if (t < 128) sb[t] = (t < NB_SCAN) ? bsum[t] : 0;
    __syncthreads();
    for (int off = 1; off < 128; off <<= 1) {
        int u = (t < 128 && t >= off) ? sb[t - off] : 0;
        __syncthreads();
        if (t < 128) sb[t] += u;
        __syncthreads();
    }
    int boff = (blockIdx.x == 0) ? 0 : sb[blockIdx.x - 1];   // exclusive block offset
    int i = blockIdx.x * 256 + t;
    if (i < NN) {
        int run = boff + lp[i];
        row_ptr[i] = run;
#pragma unroll
        for (int c = 0; c < NC; ++c) {
            cursor[c * NN + i] = run;
            run += cnt[c * NN + i];
        }
    }
    if (i == 0) row_ptr[NN] = NE;
}

__global__ void place_kernel(const int* __restrict__ src, const int* __restrict__ dst,
                             int* __restrict__ cursor, int2* __restrict__ adj) {
    int i = blockIdx.x * blockDim.x + threadIdx.x;
    if (i < NE) {
        int d = dst[i];
        int pos = atomicAdd(&cursor[(i / CHUNK) * NN + d], 1);
        adj[pos] = make_int2(src[i], i);
    }
}

// esum[v] = sum of incoming-edge features (round-invariant); also degf.
__global__ __launch_bounds__(256) void esum_csr_kernel(
        const float* __restrict__ ef, const int* __restrict__ row_ptr,
        const int2* __restrict__ adj, float* __restrict__ esum,
        float* __restrict__ degf) {
    int wid = threadIdx.x >> 6, lane = threadIdx.x & 63;
    int v = blockIdx.x * 4 + wid;
    if (v >= NN) return;
    int rp0 = row_ptr[v], rp1 = row_ptr[v + 1];
    int q = lane >> 2;
    int fo = (lane & 3) << 2;
    float4 a0 = make_float4(0.f, 0.f, 0.f, 0.f), a1 = a0;
    int i = rp0 + q;
    for (; i + 16 < rp1; i += 32) {
        int e0 = adj[i].y, e1 = adj[i + 16].y;
        float4 x0 = *(const float4*)(ef + (size_t)e0 * 16 + fo);
        float4 x1 = *(const float4*)(ef + (size_t)e1 * 16 + fo);
        a0.x += x0.x; a0.y += x0.y; a0.z += x0.z; a0.w += x0.w;
        a1.x += x1.x; a1.y += x1.y; a1.z += x1.z; a1.w += x1.w;
    }
    for (; i < rp1; i += 16) {
        int e = adj[i].y;
        float4 x = *(const float4*)(ef + (size_t)e * 16 + fo);
        a0.x += x.x; a0.y += x.y; a0.z += x.z; a0.w += x.w;
    }
    a0.x += a1.x; a0.y += a1.y; a0.z += a1.z; a0.w += a1.w;
#pragma unroll
    for (int m = 4; m < 64; m <<= 1) {
        a0.x += __shfl_xor(a0.x, m);
        a0.y += __shfl_xor(a0.y, m);
        a0.z += __shfl_xor(a0.z, m);
        a0.w += __shfl_xor(a0.w, m);
    }
    if (lane < 4) *(float4*)(esum + (size_t)v * 16 + fo) = a0;
    if (lane == 0) degf[v] = (float)(rp1 - rp0);
}

// Fold: WcT[t][j][k] = sum_m W_msg[t][k][m] * W_ih[t][j][m]   (j<192, k<144)
//       bvec[t][j]   = sum_m b_msg[t][m]    * W_ih[t][j][m]
__global__ __launch_bounds__(192) void fold_kernel(
        const float* __restrict__ W_msg, const float* __restrict__ b_msg,
        const float* __restrict__ W_ih, float* __restrict__ WcT,
        float* __restrict__ bvec) {
    __shared__ float ldsW[64][193];
    int t = blockIdx.x / 9;
    int k0 = (blockIdx.x % 9) * 16;
    int j = threadIdx.x;
    float acc[16];
#pragma unroll
    for (int kk = 0; kk < 16; ++kk) acc[kk] = 0.f;
    float bacc = 0.f;
    for (int mc = 0; mc < 2; ++mc) {
        for (int i = threadIdx.x; i < 192 * 64; i += 192) {
            int jj = i >> 6, mm = i & 63;
            ldsW[mm][jj] = W_ih[((size_t)t * 192 + jj) * 128 + mc * 64 + mm];
        }
        __syncthreads();
        for (int mm = 0; mm < 64; ++mm) {
            float wl = ldsW[mm][j];
            float bm = b_msg[t * 128 + mc * 64 + mm];
            bacc = fmaf(bm, wl, bacc);
#pragma unroll
            for (int kk = 0; kk < 16; ++kk) {
                float wm = W_msg[((size_t)t * 144 + k0 + kk) * 128 + mc * 64 + mm];
                acc[kk] = fmaf(wm, wl, acc[kk]);
            }
        }
        __syncthreads();
    }
#pragma unroll
    for (int kk = 0; kk < 16; ++kk)
        WcT[((size_t)t * 192 + j) * 144 + k0 + kk] = acc[kk];
    if (k0 == 0) bvec[t * 192 + j] = bacc;
}

// B[t][n][k] (n<256, k<224), zero-padded, biases folded — proven algebra
// (absmax 0.03125), emitted as fp16 hi/lo pair.
// A layout: [h(0:64) | S(64:128) | dgh(128:192) | esum(192:208) | deg(208) | 1(209) | 0pad]
__global__ void wbig_kernel(const float* __restrict__ WcT, const float* __restrict__ bvec,
                            const float* __restrict__ b_ih, const float* __restrict__ b_hh,
                            const float* __restrict__ W_hh,
                            unsigned short* __restrict__ Bhi, unsigned short* __restrict__ Blo) {
    int idx = blockIdx.x * 256 + threadIdx.x;
    if (idx >= 2 * 256 * KA) return;
    int t = idx / (256 * KA);
    int rem = idx % (256 * KA);
    int n = rem / KA, k = rem % KA;
    float v = 0.f;
    if (n < 192) {
        if (k < 64) {
            if (n < 128) v = W_hh[(size_t)t * 192 * 64 + n * 64 + k];
        } else if (k < 128) {
            v = WcT[((size_t)t * 192 + n) * 144 + k];
        } else if (k < 192) {
            v = WcT[((size_t)t * 192 + n) * 144 + (k - 128)];
        } else if (k < 208) {
            v = WcT[((size_t)t * 192 + n) * 144 + 128 + (k - 192)];
        } else if (k == 208) {
            v = bvec[t * 192 + n];
        } else if (k == 209) {
            v = (n < 128) ? (b_ih[t * 192 + n] + b_hh[t * 192 + n]) : b_ih[t * 192 + n];
        }
    } else {
        int j = n - 64;   // 128..191
        if (k < 64) v = W_hh[(size_t)t * 192 * 64 + j * 64 + k];
        else if (k == 209) v = b_hh[t * 192 + j];
    }
    unsigned short hi, lo;
    splitf(v, hi, lo);
    Bhi[idx] = hi;
    Blo[idx] = lo;
}

// round-invariant tail of A: [esum (16) | deg | 1 | zeros], hi/lo
__global__ void atail_kernel(const float* __restrict__ esum, const float* __restrict__ degf,
                             unsigned short* __restrict__ Ahi, unsigned short* __restrict__ Alo) {
    int i = blockIdx.x * blockDim.x + threadIdx.x;
    if (i >= NN * 32) return;
    int v = i >> 5, k = 192 + (i & 31);
    float val;
    if (k < 208) val = esum[(size_t)v * 16 + (k - 192)];
    else if (k == 208) val = degf[v];
    else if (k == 209) val = 1.f;
    else val = 0.f;
    unsigned short hi, lo;
    splitf(val, hi, lo);
    Ahi[(size_t)v * KA + k] = hi;
    Alo[(size_t)v * KA + k] = lo;
}

// ---------------- per-round ----------------
// A[v][0:192) = [ h | S = sum_src h_f16 | deg*h ], written as fp16 hi/lo pair.
__global__ __launch_bounds__(256) void gather_kernel(
        const float* __restrict__ hv, const unsigned short* __restrict__ hf,
        const int* __restrict__ row_ptr, const int2* __restrict__ adj,
        unsigned short* __restrict__ Ahi, unsigned short* __restrict__ Alo) {
    int wid = threadIdx.x >> 6, lane = threadIdx.x & 63;
    int v = blockIdx.x * 4 + wid;
    if (v >= NN) return;
    int rp0 = row_ptr[v], rp1 = row_ptr[v + 1];
    int q = lane >> 4;
    int fo = (lane & 15) << 2;           // 4 halfs (8B) per lane
    float4 acc[8];
#pragma unroll
    for (int u = 0; u < 8; ++u) acc[u] = make_float4(0.f, 0.f, 0.f, 0.f);
    int i = rp0 + q;
    for (; i + 28 < rp1; i += 32) {
        int s[8];
#pragma unroll
        for (int u = 0; u < 8; ++u) s[u] = adj[i + 4 * u].x;
#pragma unroll
        for (int u = 0; u < 8; ++u) {
            ushort4 x = *(const ushort4*)(hf + (size_t)s[u] * 64 + fo);
            acc[u].x += h2f(x.x); acc[u].y += h2f(x.y);
            acc[u].z += h2f(x.z); acc[u].w += h2f(x.w);
        }
    }
    for (; i + 4 < rp1; i += 8) {
        int s0 = adj[i].x, s1 = adj[i + 4].x;
        ushort4 x0 = *(const ushort4*)(hf + (size_t)s0 * 64 + fo);
        ushort4 x1 = *(const ushort4*)(hf + (size_t)s1 * 64 + fo);
        acc[0].x += h2f(x0.x); acc[0].y += h2f(x0.y);
        acc[0].z += h2f(x0.z); acc[0].w += h2f(x0.w);
        acc[1].x += h2f(x1.x); acc[1].y += h2f(x1.y);
        acc[1].z += h2f(x1.z); acc[1].w += h2f(x1.w);
    }
    for (; i < rp1; i += 4) {
        int s = adj[i].x;
        ushort4 x = *(const ushort4*)(hf + (size_t)s * 64 + fo);
        acc[0].x += h2f(x.x); acc[0].y += h2f(x.y);
        acc[0].z += h2f(x.z); acc[0].w += h2f(x.w);
    }
#pragma unroll
    for (int u = 1; u < 8; ++u) {
        acc[0].x += acc[u].x; acc[0].y += acc[u].y;
        acc[0].z += acc[u].z; acc[0].w += acc[u].w;
    }
#pragma unroll
    for (int m = 16; m < 64; m <<= 1) {
        acc[0].x += __shfl_xor(acc[0].x, m);
        acc[0].y += __shfl_xor(acc[0].y, m);
        acc[0].z += __shfl_xor(acc[0].z, m);
        acc[0].w += __shfl_xor(acc[0].w, m);
    }
    if (lane < 16) {
        float dg = (float)(rp1 - rp0);
        float4 hvv = *(const float4*)(hv + (size_t)v * 64 + fo);
        float4 dv = make_float4(dg * hvv.x, dg * hvv.y, dg * hvv.z, dg * hvv.w);
        ushort4 hh, hl, sh, sl, dh, dl;
        splitf(hvv.x, hh.x, hl.x); splitf(hvv.y, hh.y, hl.y);
        splitf(hvv.z, hh.z, hl.z); splitf(hvv.w, hh.w, hl.w);
        splitf(acc[0].x, sh.x, sl.x); splitf(acc[0].y, sh.y, sl.y);
        splitf(acc[0].z, sh.z, sl.z); splitf(acc[0].w, sh.w, sl.w);
        splitf(dv.x, dh.x, dl.x); splitf(dv.y, dh.y, dl.y);
        splitf(dv.z, dh.z, dl.z); splitf(dv.w, dh.w, dl.w);
        *(ushort4*)(Ahi + (size_t)v * KA + fo) = hh;
        *(ushort4*)(Alo + (size_t)v * KA + fo) = hl;
        *(ushort4*)(Ahi + (size_t)v * KA + 64 + fo) = sh;
        *(ushort4*)(Alo + (size_t)v * KA + 64 + fo) = sl;
        *(ushort4*)(Ahi + (size_t)v * KA + 128 + fo) = dh;
        *(ushort4*)(Alo + (size_t)v * KA + 128 + fo) = dl;
    }
}

// Fused MFMA GEMM (64x256 tile, 256 thr, grid 314 — full-chip coverage vs R12's
// 157) + in-register GRU gates. fp16 two-term split: C = Ahi*Bhi + Ahi*Blo +
// Alo*Bhi (~fp32). ks loop NOT unrolled (R8 spill lesson).
__global__ __launch_bounds__(256) void gemm_gru(
        const _Float16* __restrict__ Ahi, const _Float16* __restrict__ Alo,
        const _Float16* __restrict__ Bhi, const _Float16* __restrict__ Blo,
        const float* __restrict__ hin,
        float* __restrict__ fout, unsigned short* __restrict__ hfout) {
    __shared__ _Float16 Ash[64][40];    // +8 pad
    __shared__ _Float16 Asl[64][40];
    __shared__ _Float16 Bsh[256][40];
    __shared__ _Float16 Bsl[256][40];
    int tid = threadIdx.x;
    int w = tid >> 6, l = tid & 63;
    int row0 = blockIdx.x * 64;
    f32x4 acc[16];
#pragma unroll
    for (int i = 0; i < 16; ++i) acc[i] = (f32x4){0.f, 0.f, 0.f, 0.f};

#pragma unroll 1
    for (int ks = 0; ks < 7; ++ks) {
        int k0 = ks * 32;
        {   // stage A hi/lo: 64 rows x 32 halfs each (1 float4 per thread per buf)
            int r = tid >> 2, c = (tid & 3) * 8;
            *(float4*)&Ash[r][c] = *(const float4*)(Ahi + (size_t)(row0 + r) * KA + k0 + c);
            *(float4*)&Asl[r][c] = *(const float4*)(Alo + (size_t)(row0 + r) * KA + k0 + c);
        }
        {   // stage B hi/lo: 256 rows x 32 halfs each (4 float4 per thread per buf)
            int n = tid;
            const float4* ph = (const float4*)(Bhi + (size_t)n * KA + k0);
            float4 h0 = ph[0], h1 = ph[1], h2 = ph[2], h3 = ph[3];
            *(float4*)&Bsh[n][0] = h0;  *(float4*)&Bsh[n][8] = h1;
            *(float4*)&Bsh[n][16] = h2; *(float4*)&Bsh[n][24] = h3;
            const float4* pl = (const float4*)(Blo + (size_t)n * KA + k0);
            float4 l0 = pl[0], l1 = pl[1], l2 = pl[2], l3 = pl[3];
            *(float4*)&Bsl[n][0] = l0;  *(float4*)&Bsl[n][8] = l1;
            *(float4*)&Bsl[n][16] = l2; *(float4*)&Bsl[n][24] = l3;
        }
        __syncthreads();
        int kg = (l >> 4) * 8;
        int ar = w * 16 + (l & 15);
        f16x8 ah = *(const f16x8*)&Ash[ar][kg];
        f16x8 al = *(const f16x8*)&Asl[ar][kg];
#pragma unroll
        for (int fn = 0; fn < 16; ++fn) {
            f16x8 bh = *(const f16x8*)&Bsh[fn * 16 + (l & 15)][kg];
            f16x8 bl = *(const f16x8*)&Bsl[fn * 16 + (l & 15)][kg];
            acc[fn] = __builtin_amdgcn_mfma_f32_16x16x32_f16(ah, bh, acc[fn], 0, 0, 0);
            acc[fn] = __builtin_amdgcn_mfma_f32_16x16x32_f16(ah, bl, acc[fn], 0, 0, 0);
            acc[fn] = __builtin_amdgcn_mfma_f32_16x16x32_f16(al, bh, acc[fn], 0, 0, 0);
        }
        __syncthreads();
    }

    // epilogue: lane l, reg q -> row = w*16 + (l>>4)*4 + q; col j = (l&15)+16*fj
    // acc[fj]=r, acc[4+fj]=z, acc[8+fj]=i_n, acc[12+fj]=h_n (biases pre-folded)
    int jb = l & 15;
#pragma unroll
    for (int q = 0; q < 4; ++q) {
        int row = row0 + w * 16 + (l >> 4) * 4 + q;
        if (row >= NN) continue;
#pragma unroll
        for (int fj = 0; fj < 4; ++fj) {
            int j = jb + fj * 16;
            float rr = acc[fj][q];
            float zz = acc[4 + fj][q];
            float in_ = acc[8 + fj][q];
            float hn = acc[12 + fj][q];
            float r = 1.f / (1.f + __expf(-rr));
            float z = 1.f / (1.f + __expf(-zz));
            float n = tanhf(in_ + r * hn);
            float h = hin[(size_t)row * 64 + j];
            float val = (1.f - z) * n + z * h;
            fout[(size_t)row * 64 + j] = val;
            hfout[(size_t)row * 64 + j] = f2h(val);
        }
    }
}

extern "C" void kernel_launch(void* const* d_in, const int* in_sizes, int n_in,
                              void* d_out, int out_size, void* d_ws, size_t ws_size,
                              hipStream_t stream) {
    const float* hv0   = (const float*)d_in[0];
    const float* ef    = (const float*)d_in[1];
    const int*   src   = (const int*)d_in[2];
    const int*   dst   = (const int*)d_in[3];
    const float* W_msg = (const float*)d_in[4];
    const float* b_msg = (const float*)d_in[5];
    const float* W_ih  = (const float*)d_in[6];
    const float* W_hh  = (const float*)d_in[7];
    const float* b_ih  = (const float*)d_in[8];
    const float* b_hh  = (const float*)d_in[9];
    float* out = (float*)d_out;

    char* ws = (char*)d_ws;
    size_t off = 0;
    auto alloc = [&](size_t bytes) -> char* {
        char* p = ws + off;
        off = (off + bytes + 255) & ~(size_t)255;
        return p;
    };
    int*   cnt      = (int*)alloc((size_t)NC * NN * 4);
    int*   row_ptr  = (int*)alloc((NN + 1) * 4);
    int*   cursor   = (int*)alloc((size_t)NC * NN * 4);
    int2*  adj      = (int2*)alloc((size_t)NE * 8);
    float* esum     = (float*)alloc((size_t)NN * 16 * 4);
    float* degf     = (float*)alloc(NN * 4);
    float* WcT      = (float*)alloc((size_t)2 * 192 * 144 * 4);
    float* bvec     = (float*)alloc(2 * 192 * 4);
    int*   lp       = (int*)alloc(NN * 4);
    int*   bsum     = (int*)alloc(NB_SCAN * 4);
    unsigned short* Ahi = (unsigned short*)alloc((size_t)MP * KA * 2);
    unsigned short* Alo = (unsigned short*)alloc((size_t)MP * KA * 2);
    unsigned short* Bhi = (unsigned short*)alloc((size_t)2 * 256 * KA * 2);
    unsigned short* Blo = (unsigned short*)alloc((size_t)2 * 256 * KA * 2);
    float* hv1      = (float*)alloc((size_t)NN * 64 * 4);
    unsigned short* hf0 = (unsigned short*)alloc((size_t)NN * 64 * 2);
    unsigned short* hf1 = (unsigned short*)alloc((size_t)NN * 64 * 2);

    init_kernel<<<(NN * 64 + 255) / 256, 256, 0, stream>>>(hv0, hf0, cnt);
    hist_kernel<<<(NE + 255) / 256, 256, 0, stream>>>(dst, cnt);
    scan1_kernel<<<NB_SCAN, 256, 0, stream>>>(cnt, lp, bsum);
    scan3_kernel<<<NB_SCAN, 256, 0, stream>>>(cnt, lp, bsum, row_ptr, cursor);
    place_kernel<<<(NE + 255) / 256, 256, 0, stream>>>(src, dst, cursor, adj);
    esum_csr_kernel<<<(NN + 3) / 4, 256, 0, stream>>>(ef, row_ptr, adj, esum, degf);
    fold_kernel<<<18, 192, 0, stream>>>(W_msg, b_msg, W_ih, WcT, bvec);
    wbig_kernel<<<(2 * 256 * KA + 255) / 256, 256, 0, stream>>>(WcT, bvec, b_ih, b_hh,
                                                                W_hh, Bhi, Blo);
    atail_kernel<<<(NN * 32 + 255) / 256, 256, 0, stream>>>(esum, degf, Ahi, Alo);

    for (int t = 0; t < 2; ++t) {
        const float* hin = (t == 0) ? hv0 : hv1;
        const unsigned short* hfin = (t == 0) ? hf0 : hf1;
        float* hout = (t == 1) ? out : hv1;
        gather_kernel<<<(NN + 3) / 4, 256, 0, stream>>>(hin, hfin, row_ptr, adj, Ahi, Alo);
        gemm_gru<<<MP / 64, 256, 0, stream>>>(
            (const _Float16*)Ahi, (const _Float16*)Alo,
            (const _Float16*)(Bhi + (size_t)t * 256 * KA),
            (const _Float16*)(Blo + (size_t)t * 256 * KA),
            hin, hout, hf1);
    }
}

// Round 14
// 197.962 us; speedup vs baseline: 10.7750x; 1.0461x over previous
//
#include <hip/hip_runtime.h>
#include <cstddef>
#include <cstdint>

#define NN 20000
#define NE 640000
#define MP 20096       // padded rows (314*64)
#define KA 224         // A row length (halfs)
#define NC 16
#define CHUNK 40000    // NE / NC
#define NB_SCAN 79     // ceil(NN/256)

typedef _Float16 f16x8 __attribute__((ext_vector_type(8)));
typedef float f32x4 __attribute__((ext_vector_type(4)));

__device__ __forceinline__ float h2f(unsigned short u) {
    _Float16 h;
    *reinterpret_cast<unsigned short*>(&h) = u;
    return (float)h;
}
__device__ __forceinline__ unsigned short f2h(float f) {
    _Float16 h = (_Float16)f;
    return *reinterpret_cast<unsigned short*>(&h);
}
// fp16 two-term split: x ~= hi + lo (22 effective mantissa bits)
__device__ __forceinline__ void splitf(float x, unsigned short& hi, unsigned short& lo) {
    _Float16 h = (_Float16)x;
    _Float16 l = (_Float16)(x - (float)h);
    hi = *reinterpret_cast<unsigned short*>(&h);
    lo = *reinterpret_cast<unsigned short*>(&l);
}

// ---------------- setup ----------------
__global__ void init_kernel(const float* __restrict__ hv0, unsigned short* __restrict__ hf0,
                            int* __restrict__ cnt) {
    int i = blockIdx.x * blockDim.x + threadIdx.x;
    if (i < NC * NN) cnt[i] = 0;
    if (i < NN * 64) hf0[i] = f2h(hv0[i]);
}

__global__ void hist_kernel(const int* __restrict__ dst, int* __restrict__ cnt) {
    int i = blockIdx.x * blockDim.x + threadIdx.x;
    if (i < NE) atomicAdd(&cnt[(i / CHUNK) * NN + dst[i]], 1);
}

__global__ __launch_bounds__(256) void scan1_kernel(const int* __restrict__ cnt,
                                                    int* __restrict__ lp,
                                                    int* __restrict__ bsum) {
    __shared__ int s[256];
    int t = threadIdx.x;
    int i = blockIdx.x * 256 + t;
    int d = 0;
    if (i < NN)
#pragma unroll
        for (int c = 0; c < NC; ++c) d += cnt[c * NN + i];
    s[t] = d;
    __syncthreads();
    for (int off = 1; off < 256; off <<= 1) {
        int v = (t >= off) ? s[t - off] : 0;
        __syncthreads();
        s[t] += v;
        __syncthreads();
    }
    if (i < NN) lp[i] = s[t] - d;
    if (t == 255) bsum[blockIdx.x] = s[255];
}

__global__ __launch_bounds__(256) void scan3_kernel(const int* __restrict__ cnt,
                                                    const int* __restrict__ lp,
                                                    const int* __restrict__ bsum,
                                                    int* __restrict__ row_ptr,
                                                    int* __restrict__ cursor) {
    __shared__ int sb[128];
    int t = threadIdx.x;
    if (t < 128) sb[t] = (t < NB_SCAN) ? bsum[t] : 0;
    __syncthreads();
    for (int off = 1; off < 128; off <<= 1) {
        int u = (t < 128 && t >= off) ? sb[t - off] : 0;
        __syncthreads();
        if (t < 128) sb[t] += u;
        __syncthreads();
    }
    int boff = (blockIdx.x == 0) ? 0 : sb[blockIdx.x - 1];
    int i = blockIdx.x * 256 + t;
    if (i < NN) {
        int run = boff + lp[i];
        row_ptr[i] = run;
#pragma unroll
        for (int c = 0; c < NC; ++c) {
            cursor[c * NN + i] = run;
            run += cnt[c * NN + i];
        }
    }
    if (i == 0) row_ptr[NN] = NE;
}

__global__ void place_kernel(const int* __restrict__ src, const int* __restrict__ dst,
                             int* __restrict__ cursor, int2* __restrict__ adj) {
    int i = blockIdx.x * blockDim.x + threadIdx.x;
    if (i < NE) {
        int d = dst[i];
        int pos = atomicAdd(&cursor[(i / CHUNK) * NN + d], 1);
        adj[pos] = make_int2(src[i], i);
    }
}

// esum[v] = sum of incoming-edge features (round-invariant); also degf.
__global__ __launch_bounds__(256) void esum_csr_kernel(
        const float* __restrict__ ef, const int* __restrict__ row_ptr,
        const int2* __restrict__ adj, float* __restrict__ esum,
        float* __restrict__ degf) {
    int wid = threadIdx.x >> 6, lane = threadIdx.x & 63;
    int v = blockIdx.x * 4 + wid;
    if (v >= NN) return;
    int rp0 = row_ptr[v], rp1 = row_ptr[v + 1];
    int q = lane >> 2;
    int fo = (lane & 3) << 2;
    float4 a0 = make_float4(0.f, 0.f, 0.f, 0.f), a1 = a0;
    int i = rp0 + q;
    for (; i + 16 < rp1; i += 32) {
        int e0 = adj[i].y, e1 = adj[i + 16].y;
        float4 x0 = *(const float4*)(ef + (size_t)e0 * 16 + fo);
        float4 x1 = *(const float4*)(ef + (size_t)e1 * 16 + fo);
        a0.x += x0.x; a0.y += x0.y; a0.z += x0.z; a0.w += x0.w;
        a1.x += x1.x; a1.y += x1.y; a1.z += x1.z; a1.w += x1.w;
    }
    for (; i < rp1; i += 16) {
        int e = adj[i].y;
        float4 x = *(const float4*)(ef + (size_t)e * 16 + fo);
        a0.x += x.x; a0.y += x.y; a0.z += x.z; a0.w += x.w;
    }
    a0.x += a1.x; a0.y += a1.y; a0.z += a1.z; a0.w += a1.w;
#pragma unroll
    for (int m = 4; m < 64; m <<= 1) {
        a0.x += __shfl_xor(a0.x, m);
        a0.y += __shfl_xor(a0.y, m);
        a0.z += __shfl_xor(a0.z, m);
        a0.w += __shfl_xor(a0.w, m);
    }
    if (lane < 4) *(float4*)(esum + (size_t)v * 16 + fo) = a0;
    if (lane == 0) degf[v] = (float)(rp1 - rp0);
}

// Fold: WcT[t][j][k] = sum_m W_msg[t][k][m] * W_ih[t][j][m]   (j<192, k<144)
//       bvec[t][j]   = sum_m b_msg[t][m]    * W_ih[t][j][m]
__global__ __launch_bounds__(192) void fold_kernel(
        const float* __restrict__ W_msg, const float* __restrict__ b_msg,
        const float* __restrict__ W_ih, float* __restrict__ WcT,
        float* __restrict__ bvec) {
    __shared__ float ldsW[64][193];
    int t = blockIdx.x / 9;
    int k0 = (blockIdx.x % 9) * 16;
    int j = threadIdx.x;
    float acc[16];
#pragma unroll
    for (int kk = 0; kk < 16; ++kk) acc[kk] = 0.f;
    float bacc = 0.f;
    for (int mc = 0; mc < 2; ++mc) {
        for (int i = threadIdx.x; i < 192 * 64; i += 192) {
            int jj = i >> 6, mm = i & 63;
            ldsW[mm][jj] = W_ih[((size_t)t * 192 + jj) * 128 + mc * 64 + mm];
        }
        __syncthreads();
        for (int mm = 0; mm < 64; ++mm) {
            float wl = ldsW[mm][j];
            float bm = b_msg[t * 128 + mc * 64 + mm];
            bacc = fmaf(bm, wl, bacc);
#pragma unroll
            for (int kk = 0; kk < 16; ++kk) {
                float wm = W_msg[((size_t)t * 144 + k0 + kk) * 128 + mc * 64 + mm];
                acc[kk] = fmaf(wm, wl, acc[kk]);
            }
        }
        __syncthreads();
    }
#pragma unroll
    for (int kk = 0; kk < 16; ++kk)
        WcT[((size_t)t * 192 + j) * 144 + k0 + kk] = acc[kk];
    if (k0 == 0) bvec[t * 192 + j] = bacc;
}

// B[t][n][k] (n<256, k<224), zero-padded, biases folded — proven algebra,
// fp16 hi/lo pair (lo consumed only for k in [128,224) by gemm phases 4-6).
__global__ void wbig_kernel(const float* __restrict__ WcT, const float* __restrict__ bvec,
                            const float* __restrict__ b_ih, const float* __restrict__ b_hh,
                            const float* __restrict__ W_hh,
                            unsigned short* __restrict__ Bhi, unsigned short* __restrict__ Blo) {
    int idx = blockIdx.x * 256 + threadIdx.x;
    if (idx >= 2 * 256 * KA) return;
    int t = idx / (256 * KA);
    int rem = idx % (256 * KA);
    int n = rem / KA, k = rem % KA;
    float v = 0.f;
    if (n < 192) {
        if (k < 64) {
            if (n < 128) v = W_hh[(size_t)t * 192 * 64 + n * 64 + k];
        } else if (k < 128) {
            v = WcT[((size_t)t * 192 + n) * 144 + k];
        } else if (k < 192) {
            v = WcT[((size_t)t * 192 + n) * 144 + (k - 128)];
        } else if (k < 208) {
            v = WcT[((size_t)t * 192 + n) * 144 + 128 + (k - 192)];
        } else if (k == 208) {
            v = bvec[t * 192 + n];
        } else if (k == 209) {
            v = (n < 128) ? (b_ih[t * 192 + n] + b_hh[t * 192 + n]) : b_ih[t * 192 + n];
        }
    } else {
        int j = n - 64;   // 128..191
        if (k < 64) v = W_hh[(size_t)t * 192 * 64 + j * 64 + k];
        else if (k == 209) v = b_hh[t * 192 + j];
    }
    unsigned short hi, lo;
    splitf(v, hi, lo);
    Bhi[idx] = hi;
    Blo[idx] = lo;
}

// round-invariant tail of A: [esum (16) | deg | 1 | zeros] — hi only
// (phase 6 uses ah*bh + ah*bl; A-lo unused there)
__global__ void atail_kernel(const float* __restrict__ esum, const float* __restrict__ degf,
                             unsigned short* __restrict__ Ahi) {
    int i = blockIdx.x * blockDim.x + threadIdx.x;
    if (i >= NN * 32) return;
    int v = i >> 5, k = 192 + (i & 31);
    float val;
    if (k < 208) val = esum[(size_t)v * 16 + (k - 192)];
    else if (k == 208) val = degf[v];
    else if (k == 209) val = 1.f;
    else val = 0.f;
    Ahi[(size_t)v * KA + k] = f2h(val);
}

// ---------------- per-round ----------------
// A[v][0:192) = [ h | S | deg*h ]; only the dgh block (amplified path) gets a
// hi/lo split — h and S are plain fp16 (error budget per R6/R7 calibration).
__global__ __launch_bounds__(256) void gather_kernel(
        const float* __restrict__ hv, const unsigned short* __restrict__ hf,
        const int* __restrict__ row_ptr, const int2* __restrict__ adj,
        unsigned short* __restrict__ Ahi, unsigned short* __restrict__ Alo) {
    int wid = threadIdx.x >> 6, lane = threadIdx.x & 63;
    int v = blockIdx.x * 4 + wid;
    if (v >= NN) return;
    int rp0 = row_ptr[v], rp1 = row_ptr[v + 1];
    int q = lane >> 4;
    int fo = (lane & 15) << 2;           // 4 halfs (8B) per lane
    float4 acc[8];
#pragma unroll
    for (int u = 0; u < 8; ++u) acc[u] = make_float4(0.f, 0.f, 0.f, 0.f);
    int i = rp0 + q;
    for (; i + 28 < rp1; i += 32) {
        int s[8];
#pragma unroll
        for (int u = 0; u < 8; ++u) s[u] = adj[i + 4 * u].x;
#pragma unroll
        for (int u = 0; u < 8; ++u) {
            ushort4 x = *(const ushort4*)(hf + (size_t)s[u] * 64 + fo);
            acc[u].x += h2f(x.x); acc[u].y += h2f(x.y);
            acc[u].z += h2f(x.z); acc[u].w += h2f(x.w);
        }
    }
    for (; i + 4 < rp1; i += 8) {
        int s0 = adj[i].x, s1 = adj[i + 4].x;
        ushort4 x0 = *(const ushort4*)(hf + (size_t)s0 * 64 + fo);
        ushort4 x1 = *(const ushort4*)(hf + (size_t)s1 * 64 + fo);
        acc[0].x += h2f(x0.x); acc[0].y += h2f(x0.y);
        acc[0].z += h2f(x0.z); acc[0].w += h2f(x0.w);
        acc[1].x += h2f(x1.x); acc[1].y += h2f(x1.y);
        acc[1].z += h2f(x1.z); acc[1].w += h2f(x1.w);
    }
    for (; i < rp1; i += 4) {
        int s = adj[i].x;
        ushort4 x = *(const ushort4*)(hf + (size_t)s * 64 + fo);
        acc[0].x += h2f(x.x); acc[0].y += h2f(x.y);
        acc[0].z += h2f(x.z); acc[0].w += h2f(x.w);
    }
#pragma unroll
    for (int u = 1; u < 8; ++u) {
        acc[0].x += acc[u].x; acc[0].y += acc[u].y;
        acc[0].z += acc[u].z; acc[0].w += acc[u].w;
    }
#pragma unroll
    for (int m = 16; m < 64; m <<= 1) {
        acc[0].x += __shfl_xor(acc[0].x, m);
        acc[0].y += __shfl_xor(acc[0].y, m);
        acc[0].z += __shfl_xor(acc[0].z, m);
        acc[0].w += __shfl_xor(acc[0].w, m);
    }
    if (lane < 16) {
        float dg = (float)(rp1 - rp0);
        float4 hvv = *(const float4*)(hv + (size_t)v * 64 + fo);
        float4 dv = make_float4(dg * hvv.x, dg * hvv.y, dg * hvv.z, dg * hvv.w);
        ushort4 hh, sh, dh, dl;
        hh.x = f2h(hvv.x); hh.y = f2h(hvv.y); hh.z = f2h(hvv.z); hh.w = f2h(hvv.w);
        sh.x = f2h(acc[0].x); sh.y = f2h(acc[0].y);
        sh.z = f2h(acc[0].z); sh.w = f2h(acc[0].w);
        splitf(dv.x, dh.x, dl.x); splitf(dv.y, dh.y, dl.y);
        splitf(dv.z, dh.z, dl.z); splitf(dv.w, dh.w, dl.w);
        *(ushort4*)(Ahi + (size_t)v * KA + fo) = hh;
        *(ushort4*)(Ahi + (size_t)v * KA + 64 + fo) = sh;
        *(ushort4*)(Ahi + (size_t)v * KA + 128 + fo) = dh;
        *(ushort4*)(Alo + (size_t)v * KA + 128 + fo) = dl;
    }
}

// Fused MFMA GEMM (64x256 tile, 256 thr, grid 314) + in-register GRU gates.
// Selective precision (error budget per R6-pass/R7-fail calibration):
//   phases 0-3 (h,S):   1 MFMA  (ah*bh)            — stage Ash,Bsh only
//   phases 4-5 (dgh):   3 MFMA  (hi/lo both sides) — the x25-amplified path
//   phase  6  (tail):   2 MFMA  (ah*bh + ah*bl)    — A near-exact there
// Sections are separate straight-line loops (R9/R10: no masks in inner loop).
__global__ __launch_bounds__(256) void gemm_gru(
        const _Float16* __restrict__ Ahi, const _Float16* __restrict__ Alo,
        const _Float16* __restrict__ Bhi, const _Float16* __restrict__ Blo,
        const float* __restrict__ hin,
        float* __restrict__ fout, unsigned short* __restrict__ hfout) {
    __shared__ _Float16 Ash[64][40];    // +8 pad
    __shared__ _Float16 Asl[64][40];
    __shared__ _Float16 Bsh[256][40];
    __shared__ _Float16 Bsl[256][40];
    int tid = threadIdx.x;
    int w = tid >> 6, l = tid & 63;
    int row0 = blockIdx.x * 64;
    f32x4 acc[16];
#pragma unroll
    for (int i = 0; i < 16; ++i) acc[i] = (f32x4){0.f, 0.f, 0.f, 0.f};

    int sAr = tid >> 2, sAc = (tid & 3) * 8;   // A stage indices
    int kg = (l >> 4) * 8;
    int ar = w * 16 + (l & 15);
    int lc = l & 15;

    // ---- phases 0-3: h,S blocks — hi only, 1 MFMA ----
#pragma unroll 1
    for (int ks = 0; ks < 4; ++ks) {
        int k0 = ks * 32;
        *(float4*)&Ash[sAr][sAc] = *(const float4*)(Ahi + (size_t)(row0 + sAr) * KA + k0 + sAc);
        {
            const float4* ph = (const float4*)(Bhi + (size_t)tid * KA + k0);
            float4 h0 = ph[0], h1 = ph[1], h2 = ph[2], h3 = ph[3];
            *(float4*)&Bsh[tid][0] = h0;  *(float4*)&Bsh[tid][8] = h1;
            *(float4*)&Bsh[tid][16] = h2; *(float4*)&Bsh[tid][24] = h3;
        }
        __syncthreads();
        f16x8 ah = *(const f16x8*)&Ash[ar][kg];
#pragma unroll
        for (int fn = 0; fn < 16; ++fn) {
            f16x8 bh = *(const f16x8*)&Bsh[fn * 16 + lc][kg];
            acc[fn] = __builtin_amdgcn_mfma_f32_16x16x32_f16(ah, bh, acc[fn], 0, 0, 0);
        }
        __syncthreads();
    }

    // ---- phases 4-5: dgh block — full hi/lo, 3 MFMA ----
#pragma unroll 1
    for (int ks = 4; ks < 6; ++ks) {
        int k0 = ks * 32;
        *(float4*)&Ash[sAr][sAc] = *(const float4*)(Ahi + (size_t)(row0 + sAr) * KA + k0 + sAc);
        *(float4*)&Asl[sAr][sAc] = *(const float4*)(Alo + (size_t)(row0 + sAr) * KA + k0 + sAc);
        {
            const float4* ph = (const float4*)(Bhi + (size_t)tid * KA + k0);
            float4 h0 = ph[0], h1 = ph[1], h2 = ph[2], h3 = ph[3];
            *(float4*)&Bsh[tid][0] = h0;  *(float4*)&Bsh[tid][8] = h1;
            *(float4*)&Bsh[tid][16] = h2; *(float4*)&Bsh[tid][24] = h3;
            const float4* pl = (const float4*)(Blo + (size_t)tid * KA + k0);
            float4 l0 = pl[0], l1 = pl[1], l2 = pl[2], l3 = pl[3];
            *(float4*)&Bsl[tid][0] = l0;  *(float4*)&Bsl[tid][8] = l1;
            *(float4*)&Bsl[tid][16] = l2; *(float4*)&Bsl[tid][24] = l3;
        }
        __syncthreads();
        f16x8 ah = *(const f16x8*)&Ash[ar][kg];
        f16x8 al = *(const f16x8*)&Asl[ar][kg];
#pragma unroll
        for (int fn = 0; fn < 16; ++fn) {
            f16x8 bh = *(const f16x8*)&Bsh[fn * 16 + lc][kg];
            f16x8 bl = *(const f16x8*)&Bsl[fn * 16 + lc][kg];
            acc[fn] = __builtin_amdgcn_mfma_f32_16x16x32_f16(ah, bh, acc[fn], 0, 0, 0);
            acc[fn] = __builtin_amdgcn_mfma_f32_16x16x32_f16(ah, bl, acc[fn], 0, 0, 0);
            acc[fn] = __builtin_amdgcn_mfma_f32_16x16x32_f16(al, bh, acc[fn], 0, 0, 0);
        }
        __syncthreads();
    }

    // ---- phase 6: tail (esum/deg/1/bias) — 2 MFMA (A exact-ish) ----
    {
        const int k0 = 192;
        *(float4*)&Ash[sAr][sAc] = *(const float4*)(Ahi + (size_t)(row0 + sAr) * KA + k0 + sAc);
        {
            const float4* ph = (const float4*)(Bhi + (size_t)tid * KA + k0);
            float4 h0 = ph[0], h1 = ph[1], h2 = ph[2], h3 = ph[3];
            *(float4*)&Bsh[tid][0] = h0;  *(float4*)&Bsh[tid][8] = h1;
            *(float4*)&Bsh[tid][16] = h2; *(float4*)&Bsh[tid][24] = h3;
            const float4* pl = (const float4*)(Blo + (size_t)tid * KA + k0);
            float4 l0 = pl[0], l1 = pl[1], l2 = pl[2], l3 = pl[3];
            *(float4*)&Bsl[tid][0] = l0;  *(float4*)&Bsl[tid][8] = l1;
            *(float4*)&Bsl[tid][16] = l2; *(float4*)&Bsl[tid][24] = l3;
        }
        __syncthreads();
        f16x8 ah = *(const f16x8*)&Ash[ar][kg];
#pragma unroll
        for (int fn = 0; fn < 16; ++fn) {
            f16x8 bh = *(const f16x8*)&Bsh[fn * 16 + lc][kg];
            f16x8 bl = *(const f16x8*)&Bsl[fn * 16 + lc][kg];
            acc[fn] = __builtin_amdgcn_mfma_f32_16x16x32_f16(ah, bh, acc[fn], 0, 0, 0);
            acc[fn] = __builtin_amdgcn_mfma_f32_16x16x32_f16(ah, bl, acc[fn], 0, 0, 0);
        }
        __syncthreads();
    }

    // epilogue: lane l, reg q -> row = w*16 + (l>>4)*4 + q; col j = (l&15)+16*fj
    int jb = l & 15;
#pragma unroll
    for (int q = 0; q < 4; ++q) {
        int row = row0 + w * 16 + (l >> 4) * 4 + q;
        if (row >= NN) continue;
#pragma unroll
        for (int fj = 0; fj < 4; ++fj) {
            int j = jb + fj * 16;
            float rr = acc[fj][q];
            float zz = acc[4 + fj][q];
            float in_ = acc[8 + fj][q];
            float hn = acc[12 + fj][q];
            float r = 1.f / (1.f + __expf(-rr));
            float z = 1.f / (1.f + __expf(-zz));
            float n = tanhf(in_ + r * hn);
            float h = hin[(size_t)row * 64 + j];
            float val = (1.f - z) * n + z * h;
            fout[(size_t)row * 64 + j] = val;
            hfout[(size_t)row * 64 + j] = f2h(val);
        }
    }
}

extern "C" void kernel_launch(void* const* d_in, const int* in_sizes, int n_in,
                              void* d_out, int out_size, void* d_ws, size_t ws_size,
                              hipStream_t stream) {
    const float* hv0   = (const float*)d_in[0];
    const float* ef    = (const float*)d_in[1];
    const int*   src   = (const int*)d_in[2];
    const int*   dst   = (const int*)d_in[3];
    const float* W_msg = (const float*)d_in[4];
    const float* b_msg = (const float*)d_in[5];
    const float* W_ih  = (const float*)d_in[6];
    const float* W_hh  = (const float*)d_in[7];
    const float* b_ih  = (const float*)d_in[8];
    const float* b_hh  = (const float*)d_in[9];
    float* out = (float*)d_out;

    char* ws = (char*)d_ws;
    size_t off = 0;
    auto alloc = [&](size_t bytes) -> char* {
        char* p = ws + off;
        off = (off + bytes + 255) & ~(size_t)255;
        return p;
    };
    int*   cnt      = (int*)alloc((size_t)NC * NN * 4);
    int*   row_ptr  = (int*)alloc((NN + 1) * 4);
    int*   cursor   = (int*)alloc((size_t)NC * NN * 4);
    int2*  adj      = (int2*)alloc((size_t)NE * 8);
    float* esum     = (float*)alloc((size_t)NN * 16 * 4);
    float* degf     = (float*)alloc(NN * 4);
    float* WcT      = (float*)alloc((size_t)2 * 192 * 144 * 4);
    float* bvec     = (float*)alloc(2 * 192 * 4);
    int*   lp       = (int*)alloc(NN * 4);
    int*   bsum     = (int*)alloc(NB_SCAN * 4);
    unsigned short* Ahi = (unsigned short*)alloc((size_t)MP * KA * 2);
    unsigned short* Alo = (unsigned short*)alloc((size_t)MP * KA * 2);
    unsigned short* Bhi = (unsigned short*)alloc((size_t)2 * 256 * KA * 2);
    unsigned short* Blo = (unsigned short*)alloc((size_t)2 * 256 * KA * 2);
    float* hv1      = (float*)alloc((size_t)NN * 64 * 4);
    unsigned short* hf0 = (unsigned short*)alloc((size_t)NN * 64 * 2);
    unsigned short* hf1 = (unsigned short*)alloc((size_t)NN * 64 * 2);

    init_kernel<<<(NN * 64 + 255) / 256, 256, 0, stream>>>(hv0, hf0, cnt);
    hist_kernel<<<(NE + 255) / 256, 256, 0, stream>>>(dst, cnt);
    scan1_kernel<<<NB_SCAN, 256, 0, stream>>>(cnt, lp, bsum);
    scan3_kernel<<<NB_SCAN, 256, 0, stream>>>(cnt, lp, bsum, row_ptr, cursor);
    place_kernel<<<(NE + 255) / 256, 256, 0, stream>>>(src, dst, cursor, adj);
    esum_csr_kernel<<<(NN + 3) / 4, 256, 0, stream>>>(ef, row_ptr, adj, esum, degf);
    fold_kernel<<<18, 192, 0, stream>>>(W_msg, b_msg, W_ih, WcT, bvec);
    wbig_kernel<<<(2 * 256 * KA + 255) / 256, 256, 0, stream>>>(WcT, bvec, b_ih, b_hh,
                                                                W_hh, Bhi, Blo);
    atail_kernel<<<(NN * 32 + 255) / 256, 256, 0, stream>>>(esum, degf, Ahi);

    for (int t = 0; t < 2; ++t) {
        const float* hin = (t == 0) ? hv0 : hv1;
        const unsigned short* hfin = (t == 0) ? hf0 : hf1;
        float* hout = (t == 1) ? out : hv1;
        gather_kernel<<<(NN + 3) / 4, 256, 0, stream>>>(hin, hfin, row_ptr, adj, Ahi, Alo);
        gemm_gru<<<MP / 64, 256, 0, stream>>>(
            (const _Float16*)Ahi, (const _Float16*)Alo,
            (const _Float16*)(Bhi + (size_t)t * 256 * KA),
            (const _Float16*)(Blo + (size_t)t * 256 * KA),
            hin, hout, hf1);
    }
}